// Round 2
// baseline (25502.182 us; speedup 1.0000x reference)
//
#include <hip/hip_runtime.h>
#include <hip/hip_bf16.h>
#include <hip/hip_cooperative_groups.h>

namespace cg = cooperative_groups;

// Problem dims
#define TT 512
#define BB 128
#define DD 1024
#define HH 1024
#define NG 4096    // 4*HH gate columns
#define KT 2048    // DD+HH

using bf8   = __attribute__((ext_vector_type(8))) short;   // 8 bf16 bit patterns
using f32x4 = __attribute__((ext_vector_type(4))) float;
using f32x16 = __attribute__((ext_vector_type(16))) float;

// LDS layout (dynamic):
//  [0, 131072)          Wl  : weight slice, [k8 0..255][n' 0..31][8 bf16]
//  [131072, 139264)     Abuf0 (chunk even)  [k8 0..7][row 0..63][8 bf16]  (also tmp for K-reduction)
//  [139264, 147456)     Abuf1 (chunk odd)
//  [147456, 155648)     GL  : gates [64 rows][32 n'] f32
#define AB_OFF 131072
#define AB_SZ  8192
#define GL_OFF 147456
#define SMEM_TOTAL 155648

__device__ __forceinline__ unsigned short f2bf(float f) {
  unsigned int u = __builtin_bit_cast(unsigned int, f);
  u += 0x7fffu + ((u >> 16) & 1u);   // RNE
  return (unsigned short)(u >> 16);
}
__device__ __forceinline__ float sigm(float x) { return 1.0f / (1.0f + __expf(-x)); }
__device__ __forceinline__ float ftanh(float x) {
  float e = __expf(2.0f * x);
  return 1.0f - 2.0f / (e + 1.0f);
}

// ---------------- prep kernels ----------------

__global__ void k_detect(const unsigned int* __restrict__ rw, int* __restrict__ flag) {
  __shared__ int any;
  if (threadIdx.x == 0) any = 0;
  __syncthreads();
  int loc = 0;
  for (int i = threadIdx.x; i < (TT * BB) / 4; i += blockDim.x)
    if (rw[i] > 1u) loc = 1;
  if (loc) atomicOr(&any, 1);
  __syncthreads();
  if (threadIdx.x == 0) *flag = any;
}

// Pack W = [Wx; Wh] (KT x NG, f32 row-major) into Wp[n][k] bf16 (N-major).
__global__ void k_pack(const float* __restrict__ Wx, const float* __restrict__ Wh,
                       unsigned short* __restrict__ Wp) {
  __shared__ unsigned short tile[64][65];
  const int kt = blockIdx.x & 31;   // KT/64 = 32
  const int nt = blockIdx.x >> 5;   // NG/64 = 64
  const int k0 = kt * 64, n0 = nt * 64;
  const int t = threadIdx.x;
  {
    const int kl = t >> 2;            // 0..63
    const int nl = (t & 3) * 16;
    const int kg = k0 + kl;
    const float* src = (kg < DD) ? (Wx + (size_t)kg * NG + n0 + nl)
                                 : (Wh + (size_t)(kg - DD) * NG + n0 + nl);
#pragma unroll
    for (int j = 0; j < 16; ++j) tile[kl][nl + j] = f2bf(src[j]);
  }
  __syncthreads();
  {
    const int nl = t >> 2;
    const int kl = (t & 3) * 16;
    unsigned short* dst = Wp + (size_t)(n0 + nl) * KT + k0 + kl;
#pragma unroll
    for (int j = 0; j < 16; ++j) dst[j] = tile[kl + j][nl];
  }
}

// h_buf[0] = resets[0] ? 0 : bf16(h0)
__global__ void k_init(const float* __restrict__ h0, const unsigned char* __restrict__ rB,
                       const int* __restrict__ rI, const int* __restrict__ flag,
                       unsigned short* __restrict__ hbuf) {
  const int i = blockIdx.x * 256 + threadIdx.x;
  if (i >= BB * HH) return;
  const int row = i >> 10;
  const bool r = (*flag) ? (rB[row] != 0) : (rI[row] != 0);
  hbuf[i] = r ? (unsigned short)0 : f2bf(h0[i]);
}

// ---------------- persistent scan kernel ----------------

struct XReg { f32x4 a, b, c, d; };
struct HReg { bf8 a, b; };

#define ISSUE_ANY(T_, CH, XS, HS) do {                                          \
  const int ch_ = (CH);                                                         \
  if (ch_ < 16) {                                                               \
    const float* xs_ = obs + ((size_t)(T_) * BB + row0 + sr) * DD + ch_ * 64 + kq * 16; \
    XS.a = *(const f32x4*)(xs_);      XS.b = *(const f32x4*)(xs_ + 4);          \
    XS.c = *(const f32x4*)(xs_ + 8);  XS.d = *(const f32x4*)(xs_ + 12);         \
  } else {                                                                      \
    const unsigned short* hs_ = hbuf +                                          \
        ((size_t)((T_) & 1) * BB + row0 + sr) * HH + (ch_ - 16) * 64 + kq * 16; \
    HS.a = *(const bf8*)hs_;  HS.b = *(const bf8*)(hs_ + 8);                    \
  }                                                                             \
} while (0)

#define WRITE_ANY(CH, XS, HS) do {                                              \
  const int ch_ = (CH);                                                         \
  char* d0_ = sm + AB_OFF + (ch_ & 1) * AB_SZ + (kq * 2) * 1024 + sr * 16;      \
  char* d1_ = d0_ + 1024;                                                       \
  if (ch_ < 16) {                                                               \
    bf8 lo_, hi_;                                                               \
    lo_[0]=(short)f2bf(XS.a[0]); lo_[1]=(short)f2bf(XS.a[1]);                   \
    lo_[2]=(short)f2bf(XS.a[2]); lo_[3]=(short)f2bf(XS.a[3]);                   \
    lo_[4]=(short)f2bf(XS.b[0]); lo_[5]=(short)f2bf(XS.b[1]);                   \
    lo_[6]=(short)f2bf(XS.b[2]); lo_[7]=(short)f2bf(XS.b[3]);                   \
    hi_[0]=(short)f2bf(XS.c[0]); hi_[1]=(short)f2bf(XS.c[1]);                   \
    hi_[2]=(short)f2bf(XS.c[2]); hi_[3]=(short)f2bf(XS.c[3]);                   \
    hi_[4]=(short)f2bf(XS.d[0]); hi_[5]=(short)f2bf(XS.d[1]);                   \
    hi_[6]=(short)f2bf(XS.d[2]); hi_[7]=(short)f2bf(XS.d[3]);                   \
    *(bf8*)d0_ = lo_;  *(bf8*)d1_ = hi_;                                        \
  } else {                                                                      \
    *(bf8*)d0_ = HS.a;  *(bf8*)d1_ = HS.b;                                      \
  }                                                                             \
} while (0)

#define COMPUTE(CH) do {                                                        \
  const int ch_ = (CH);                                                         \
  const char* ab_ = sm + AB_OFF + (ch_ & 1) * AB_SZ;                            \
  bf8 a0_ = *(const bf8*)(ab_ + ((wk * 2 + 0) * 2 + lhi32) * 1024 + arowb);     \
  bf8 b0_ = *(const bf8*)(sm + (ch_ * 8 + (wk * 2 + 0) * 2 + lhi32) * 512 + bcolb); \
  acc = __builtin_amdgcn_mfma_f32_32x32x16_bf16(a0_, b0_, acc, 0, 0, 0);        \
  bf8 a1_ = *(const bf8*)(ab_ + ((wk * 2 + 1) * 2 + lhi32) * 1024 + arowb);     \
  bf8 b1_ = *(const bf8*)(sm + (ch_ * 8 + (wk * 2 + 1) * 2 + lhi32) * 512 + bcolb); \
  acc = __builtin_amdgcn_mfma_f32_32x32x16_bf16(a1_, b1_, acc, 0, 0, 0);        \
} while (0)

__global__ void __launch_bounds__(256)
k_scan(const float* __restrict__ obs, const unsigned char* __restrict__ resetsB,
       const int* __restrict__ resetsI, const float* __restrict__ c0,
       const float* __restrict__ bias, const unsigned short* __restrict__ Wp,
       unsigned short* __restrict__ hbuf, const int* __restrict__ flag,
       float* __restrict__ out) {
  extern __shared__ char sm[];
  float* GL = (float*)(sm + GL_OFF);

  const int tid = threadIdx.x;
  const int wv  = tid >> 6;
  const int wm  = wv >> 1;       // M half (rows wm*32..wm*32+31)
  const int wk  = wv & 1;        // K half within each chunk
  const int ln  = tid & 63;
  const int l31 = ln & 31;
  const int lhi32 = ln >> 5;
  const int arowb = (wm * 32 + l31) * 16;   // byte offset of A row in [k8][64][8]
  const int bcolb = l31 * 16;

  const int mb  = blockIdx.x >> 7;   // 0..1
  const int jb  = blockIdx.x & 127;  // 0..127
  const int row0 = mb * 64;
  const int byteMode = *flag;

  cg::grid_group grid = cg::this_grid();

  // ---- load weight slice into LDS (once) ----
  {
    const int np  = tid >> 3;          // n' 0..31
    const int seg = tid & 7;           // 0..7
    const int g = np >> 3, jj = np & 7;
    const unsigned short* src = Wp + ((size_t)g * 1024 + jb * 8 + jj) * KT;
#pragma unroll 4
    for (int i = 0; i < 32; ++i) {
      const int k8 = seg * 32 + i;
      bf8 v = *(const bf8*)(src + k8 * 8);
      *(bf8*)(sm + k8 * 512 + np * 16) = v;
    }
  }

  // staging mapping
  const int sr = tid >> 2;      // row 0..63
  const int kq = tid & 3;       // 16-elem group within 64-K chunk

  // elementwise mapping: cells (rl, j) and (rl+32, j)
  const int j  = tid & 7;
  const int rl = tid >> 3;      // 0..31
  float b0 = bias[0 * HH + jb * 8 + j];
  float b1 = bias[1 * HH + jb * 8 + j];
  float b2 = bias[2 * HH + jb * 8 + j];
  float b3 = bias[3 * HH + jb * 8 + j];
  float c_a = c0[(size_t)(row0 + rl) * HH + jb * 8 + j];
  float c_b = c0[(size_t)(row0 + rl + 32) * HH + jb * 8 + j];

  XReg xA, xB; HReg hA, hB;

  __syncthreads();   // W in LDS ready

  // prologue for t=0
  ISSUE_ANY(0, 0, xA, hA);
  ISSUE_ANY(0, 1, xB, hB);
  WRITE_ANY(0, xA, hA);
  ISSUE_ANY(0, 2, xA, hA);
  __syncthreads();

#pragma unroll 1
  for (int t = 0; t < TT; ++t) {
    f32x16 acc = {0.f,0.f,0.f,0.f, 0.f,0.f,0.f,0.f, 0.f,0.f,0.f,0.f, 0.f,0.f,0.f,0.f};

#pragma unroll 1
    for (int c2 = 0; c2 < 16; ++c2) {
      const int che = c2 * 2;
      {  // even iter: handles odd-chunk (set B) write/issue
        WRITE_ANY(che + 1, xB, hB);
        if (c2 <= 14) ISSUE_ANY(t, che + 3, xB, hB);
        COMPUTE(che);
        __syncthreads();
      }
      {  // odd iter: handles even-chunk (set A) write/issue
        if (c2 <= 14) WRITE_ANY(che + 2, xA, hA);
        if (c2 <= 13) ISSUE_ANY(t, che + 4, xA, hA);
        COMPUTE(che + 1);
        __syncthreads();
      }
    }

    // ---- K-split reduction (tmp reuses Abuf0) ----
    if (wk == 1) {
      char* tp = sm + AB_OFF + wm * 4096;
#pragma unroll
      for (int q = 0; q < 4; ++q) {
        f32x4 v;
        v[0] = acc[q*4+0]; v[1] = acc[q*4+1]; v[2] = acc[q*4+2]; v[3] = acc[q*4+3];
        *(f32x4*)(tp + q * 1024 + ln * 16) = v;
      }
    }
    __syncthreads();
    if (wk == 0) {
      const char* tp = sm + AB_OFF + wm * 4096;
#pragma unroll
      for (int q = 0; q < 4; ++q) {
        f32x4 v = *(const f32x4*)(tp + q * 1024 + ln * 16);
        acc[q*4+0] += v[0]; acc[q*4+1] += v[1]; acc[q*4+2] += v[2]; acc[q*4+3] += v[3];
      }
      // D layout 32x32: col = lane&31, row = (reg&3) + 8*(reg>>2) + 4*(lane>>5)  [m74/m101]
#pragma unroll
      for (int r = 0; r < 16; ++r) {
        const int rowl = wm * 32 + (r & 3) + 8 * (r >> 2) + 4 * lhi32;
        GL[rowl * 32 + l31] = acc[r];
      }
    }
    __syncthreads();

    // issue next step's first two x-chunks before the grid sync (obs is h-independent)
    if (t + 1 < TT) {
      ISSUE_ANY(t + 1, 0, xA, hA);
      ISSUE_ANY(t + 1, 1, xB, hB);
    }

    // ---- elementwise LSTM update: 2 cells per thread ----
    {
      const int p = t & 1;
#pragma unroll
      for (int s = 0; s < 2; ++s) {
        const int row  = rl + s * 32;
        const int grow = row0 + row;
        const int ridx = t * BB + grow;
        const bool rcur = byteMode ? (resetsB[ridx] != 0) : (resetsI[ridx] != 0);
        float cold = (s == 0) ? c_a : c_b;
        if (rcur) cold = 0.f;
        const float ig = GL[row * 32 +      j] + b0;
        const float fg = GL[row * 32 +  8 + j] + b1;
        const float gg = GL[row * 32 + 16 + j] + b2;
        const float og = GL[row * 32 + 24 + j] + b3;
        const float nc = sigm(fg) * cold + sigm(ig) * ftanh(gg);
        const float nh = sigm(og) * ftanh(nc);
        if (s == 0) c_a = nc; else c_b = nc;
        out[(size_t)t * BB * HH + (size_t)grow * HH + jb * 8 + j] = nh;
        if (t + 1 < TT) {
          const int ridx2 = (t + 1) * BB + grow;
          const bool rnxt = byteMode ? (resetsB[ridx2] != 0) : (resetsI[ridx2] != 0);
          hbuf[((size_t)(1 - p) * BB + grow) * HH + jb * 8 + j] =
              rnxt ? (unsigned short)0 : f2bf(nh);
        } else {
          out[(size_t)TT * BB * HH + (size_t)grow * HH + jb * 8 + j] = nh;
          out[(size_t)TT * BB * HH + (size_t)BB * HH + (size_t)grow * HH + jb * 8 + j] = nc;
        }
      }
    }

    if (t + 1 < TT) {
      // prologue for t+1: write chunk0, issue chunk2 (Abuf0 free: tmp consumed above)
      WRITE_ANY(0, xA, hA);
      ISSUE_ANY(t + 1, 2, xA, hA);
      grid.sync();
      __syncthreads();
    }
  }
}

// ---------------- launch ----------------

extern "C" void kernel_launch(void* const* d_in, const int* in_sizes, int n_in,
                              void* d_out, int out_size, void* d_ws, size_t ws_size,
                              hipStream_t stream) {
  const float* obs  = (const float*)d_in[0];
  const void*  rst  = d_in[1];
  const float* h0   = (const float*)d_in[2];
  const float* c0   = (const float*)d_in[3];
  const float* Wx   = (const float*)d_in[4];
  const float* Wh   = (const float*)d_in[5];
  const float* bias = (const float*)d_in[6];
  float* out = (float*)d_out;

  char* ws = (char*)d_ws;
  unsigned short* Wp   = (unsigned short*)ws;                          // 16 MiB
  unsigned short* hbuf = (unsigned short*)(ws + (size_t)NG * KT * 2);  // 512 KiB
  int* flag = (int*)(ws + (size_t)NG * KT * 2 + (size_t)2 * BB * HH * 2);

  const unsigned char* rB = (const unsigned char*)rst;
  const int* rI = (const int*)rst;

  k_detect<<<1, 256, 0, stream>>>((const unsigned int*)rst, flag);
  k_pack<<<dim3((KT / 64) * (NG / 64)), dim3(256), 0, stream>>>(Wx, Wh, Wp);
  k_init<<<dim3((BB * HH) / 256), dim3(256), 0, stream>>>(h0, rB, rI, flag, hbuf);

  static int attr_set = 0;
  (void)attr_set;
  hipFuncSetAttribute((const void*)k_scan,
                      hipFuncAttributeMaxDynamicSharedMemorySize, SMEM_TOTAL);

  void* args[] = { (void*)&obs, (void*)&rB, (void*)&rI, (void*)&c0, (void*)&bias,
                   (void*)&Wp, (void*)&hbuf, (void*)&flag, (void*)&out };
  hipLaunchCooperativeKernel((const void*)k_scan, dim3(256), dim3(256), args,
                             SMEM_TOTAL, stream);
}

// Round 3
// 14961.169 us; speedup vs baseline: 1.7046x; 1.7046x over previous
//
#include <hip/hip_runtime.h>
#include <hip/hip_bf16.h>

// Problem dims
#define TT 512
#define BB 128
#define DD 1024
#define HH 1024
#define NG 4096    // 4*HH gate columns
#define KT 2048    // DD+HH
#define NBLK 128

using bf8    = __attribute__((ext_vector_type(8))) short;   // 8 bf16 bit patterns
using f32x4  = __attribute__((ext_vector_type(4))) float;
using f32x16 = __attribute__((ext_vector_type(16))) float;

// LDS regions (dynamic):
//  [0, 131072)        Wl : weight slice [k8 0..255][np 0..31][8 bf16]
//  [131072, 148028)   GL/TMP alias: TMP = 4 wm * 4KB (K-reduce);  GL = [128 rows][33 f32]
//  [147968, 150016)   HN : next-h staging [128 rows][8 bf16]
#define GL_OFF   131072
#define HN_OFF   147968
#define SMEM_TOTAL 150016

__device__ __forceinline__ unsigned short f2bf(float f) {
  unsigned int u = __builtin_bit_cast(unsigned int, f);
  u += 0x7fffu + ((u >> 16) & 1u);   // RNE
  return (unsigned short)(u >> 16);
}
__device__ __forceinline__ float sigm(float x) { return 1.0f / (1.0f + __expf(-x)); }
__device__ __forceinline__ float ftanh(float x) {
  float e = __expf(2.0f * x);
  return 1.0f - 2.0f / (e + 1.0f);
}

// ---------------- prep kernels ----------------

// Detect resets storage (bool-bytes vs int32) and init producer flags to 1.
__global__ void k_detect(const unsigned int* __restrict__ rw, int* __restrict__ flagmode,
                         unsigned int* __restrict__ flags) {
  __shared__ int any;
  if (threadIdx.x == 0) any = 0;
  __syncthreads();
  int loc = 0;
  for (int i = threadIdx.x; i < (TT * BB) / 4; i += blockDim.x)
    if (rw[i] > 1u) loc = 1;
  if (loc) atomicOr(&any, 1);
  __syncthreads();
  if (threadIdx.x == 0) *flagmode = any;
  if (threadIdx.x < NBLK) flags[threadIdx.x] = 1u;   // h-input for step 0 ready
}

// Pack W = [Wx; Wh] (KT x NG, f32 row-major) into Wp[n][k] bf16 (N-major).
__global__ void k_pack(const float* __restrict__ Wx, const float* __restrict__ Wh,
                       unsigned short* __restrict__ Wp) {
  __shared__ unsigned short tile[64][65];
  const int kt = blockIdx.x & 31;
  const int nt = blockIdx.x >> 5;
  const int k0 = kt * 64, n0 = nt * 64;
  const int t = threadIdx.x;
  {
    const int kl = t >> 2;
    const int nl = (t & 3) * 16;
    const int kg = k0 + kl;
    const float* src = (kg < DD) ? (Wx + (size_t)kg * NG + n0 + nl)
                                 : (Wh + (size_t)(kg - DD) * NG + n0 + nl);
#pragma unroll
    for (int j = 0; j < 16; ++j) tile[kl][nl + j] = f2bf(src[j]);
  }
  __syncthreads();
  {
    const int nl = t >> 2;
    const int kl = (t & 3) * 16;
    unsigned short* dst = Wp + (size_t)(n0 + nl) * KT + k0 + kl;
#pragma unroll
    for (int j = 0; j < 16; ++j) dst[j] = tile[kl + j][nl];
  }
}

// hbuf slot0 = resets[0] ? 0 : bf16(h0)
__global__ void k_init(const float* __restrict__ h0, const unsigned char* __restrict__ rB,
                       const int* __restrict__ rI, const int* __restrict__ flagmode,
                       unsigned short* __restrict__ hbuf) {
  const int i = blockIdx.x * 256 + threadIdx.x;
  if (i >= BB * HH) return;
  const int row = i >> 10;
  const bool r = (*flagmode) ? (rB[row] != 0) : (rI[row] != 0);
  hbuf[i] = r ? (unsigned short)0 : f2bf(h0[i]);
}

// ---------------- persistent scan kernel ----------------

#define HLD(dst, KH) asm volatile("global_load_dwordx4 %0, %1, off sc0 sc1" \
    : "=v"(dst) : "v"(hbB + (size_t)(KH) * 64) : "memory")

#define HSTEP(IT, WCA, WCB) do {                                                     \
  asm volatile("s_waitcnt vmcnt(" WCA ")" ::: "memory");                             \
  __builtin_amdgcn_sched_barrier(0);                                                 \
  { const bf8 bbA = *(const bf8*)(sm + (size_t)(128 + 8*(IT) + 2*wk + lhi)*512 + l31*16); \
    acc = __builtin_amdgcn_mfma_f32_32x32x16_bf16(hA, bbA, acc, 0, 0, 0); }          \
  if ((IT) < 15) HLD(hA, 2*(IT) + 2);                                                \
  asm volatile("s_waitcnt vmcnt(" WCB ")" ::: "memory");                             \
  __builtin_amdgcn_sched_barrier(0);                                                 \
  { const bf8 bbB = *(const bf8*)(sm + (size_t)(128 + 8*(IT) + 4 + 2*wk + lhi)*512 + l31*16); \
    acc = __builtin_amdgcn_mfma_f32_32x32x16_bf16(hB, bbB, acc, 0, 0, 0); }          \
  if ((IT) < 15) HLD(hB, 2*(IT) + 3);                                                \
} while (0)

__global__ void __launch_bounds__(512)
k_scan(const float* __restrict__ obs, const unsigned char* __restrict__ resetsB,
       const int* __restrict__ resetsI, const float* __restrict__ c0,
       const float* __restrict__ bias, const unsigned short* __restrict__ Wp,
       unsigned short* __restrict__ hbuf, unsigned int* __restrict__ flags,
       const int* __restrict__ flagmode, float* __restrict__ out) {
  extern __shared__ char sm[];
  float* GLf = (float*)(sm + GL_OFF);
  unsigned short* HNp = (unsigned short*)(sm + HN_OFF);

  const int tid = threadIdx.x;
  const int w   = tid >> 6;
  const int wm  = w >> 1;        // row-tile: rows wm*32..+31
  const int wk  = w & 1;         // K parity split
  const int ln  = tid & 63;
  const int l31 = ln & 31;
  const int lhi = ln >> 5;
  const int b   = blockIdx.x;
  const int byteMode = *flagmode;

  // ---- load weight slice into LDS (once): Wl[k8][np][8] ----
  {
    const int np_ld = tid >> 4;         // 0..31
    const int seg   = tid & 15;         // 0..15
    const int g = np_ld >> 3, jj = np_ld & 7;
    const unsigned short* src = Wp + (size_t)(g * 1024 + b * 8 + jj) * KT;
#pragma unroll 4
    for (int i = 0; i < 16; ++i) {
      const int k8 = seg * 16 + i;
      bf8 v = *(const bf8*)(src + k8 * 8);
      *(bf8*)(sm + (size_t)k8 * 512 + np_ld * 16) = v;
    }
  }

  // elementwise mapping: cells (rl, j) and (rl+64, j)
  const int j  = tid & 7;
  const int rl = tid >> 3;       // 0..63
  float c_a = c0[(size_t)rl * HH + b * 8 + j];
  float c_b = c0[(size_t)(rl + 64) * HH + b * 8 + j];

  // per-lane bias for GL write (col np = l31)
  const float wbias = bias[(l31 >> 3) * 1024 + b * 8 + (l31 & 7)];

  __syncthreads();   // Wl ready

#pragma unroll 1
  for (int t = 0; t < TT; ++t) {
    // resets for this step (loaded early; drained before h-phase)
    bool rc0, rc1, rn0 = false, rn1 = false;
    if (byteMode) {
      rc0 = resetsB[t * BB + rl] != 0;  rc1 = resetsB[t * BB + rl + 64] != 0;
      if (t + 1 < TT) { rn0 = resetsB[(t+1) * BB + rl] != 0; rn1 = resetsB[(t+1) * BB + rl + 64] != 0; }
    } else {
      rc0 = resetsI[t * BB + rl] != 0;  rc1 = resetsI[t * BB + rl + 64] != 0;
      if (t + 1 < TT) { rn0 = resetsI[(t+1) * BB + rl] != 0; rn1 = resetsI[(t+1) * BB + rl + 64] != 0; }
    }

    f32x16 acc = {0.f,0.f,0.f,0.f, 0.f,0.f,0.f,0.f, 0.f,0.f,0.f,0.f, 0.f,0.f,0.f,0.f};

    // ---- x phase: no h dependency; hides producer skew ----
    {
      const float* xbase = obs + ((size_t)t * BB + wm * 32 + l31) * DD + wk * 16 + lhi * 8;
#pragma unroll 8
      for (int ks = 0; ks < 32; ++ks) {
        const float* xp = xbase + ks * 32;
        f32x4 f0 = *(const f32x4*)xp;
        f32x4 f1 = *(const f32x4*)(xp + 4);
        uint4 cv;
        asm("v_cvt_pk_bf16_f32 %0, %1, %2" : "=v"(cv.x) : "v"(f0[0]), "v"(f0[1]));
        asm("v_cvt_pk_bf16_f32 %0, %1, %2" : "=v"(cv.y) : "v"(f0[2]), "v"(f0[3]));
        asm("v_cvt_pk_bf16_f32 %0, %1, %2" : "=v"(cv.z) : "v"(f1[0]), "v"(f1[1]));
        asm("v_cvt_pk_bf16_f32 %0, %1, %2" : "=v"(cv.w) : "v"(f1[2]), "v"(f1[3]));
        const bf8 xa = __builtin_bit_cast(bf8, cv);
        const bf8 xb = *(const bf8*)(sm + (size_t)(4 * ks + 2 * wk + lhi) * 512 + l31 * 16);
        acc = __builtin_amdgcn_mfma_f32_32x32x16_bf16(xa, xb, acc, 0, 0, 0);
      }
    }

    // ---- poll producer flags (h input for step t ready) ----
    {
      const unsigned long long* f64 = (const unsigned long long*)flags;
      const unsigned int need = (unsigned int)(t + 1);
      while (true) {
        unsigned long long v = __hip_atomic_load(&f64[ln], __ATOMIC_RELAXED,
                                                 __HIP_MEMORY_SCOPE_AGENT);
        const int ok = ((unsigned int)v >= need) && ((unsigned int)(v >> 32) >= need);
        if (__all(ok)) break;
        __builtin_amdgcn_s_sleep(2);
      }
    }
    // drain all outstanding vmem so counted-vmcnt pipeline below is exact
    asm volatile("s_waitcnt vmcnt(0)" ::: "memory");
    __builtin_amdgcn_sched_barrier(0);

    // ---- h phase: coherent loads straight to MFMA, depth-2 pipeline ----
    {
      const char* hbB = (const char*)hbuf + (size_t)(t & 1) * (BB * HH * 2)
                      + (size_t)(wm * 32 + l31) * (HH * 2) + (size_t)wk * 32 + (size_t)lhi * 16;
      bf8 hA, hB;
      HLD(hA, 0); HLD(hB, 1);
      HSTEP(0,  "1", "1");  HSTEP(1,  "1", "1");  HSTEP(2,  "1", "1");  HSTEP(3,  "1", "1");
      HSTEP(4,  "1", "1");  HSTEP(5,  "1", "1");  HSTEP(6,  "1", "1");  HSTEP(7,  "1", "1");
      HSTEP(8,  "1", "1");  HSTEP(9,  "1", "1");  HSTEP(10, "1", "1");  HSTEP(11, "1", "1");
      HSTEP(12, "1", "1");  HSTEP(13, "1", "1");  HSTEP(14, "1", "1");  HSTEP(15, "1", "0");
    }

    // ---- K-split reduce (TMP aliases GL region) ----
    if (wk == 1) {
      char* tp = sm + GL_OFF + wm * 4096 + ln * 16;
      f32x4 v0 = {acc[0], acc[1], acc[2], acc[3]};
      f32x4 v1 = {acc[4], acc[5], acc[6], acc[7]};
      f32x4 v2 = {acc[8], acc[9], acc[10], acc[11]};
      f32x4 v3 = {acc[12], acc[13], acc[14], acc[15]};
      *(f32x4*)(tp)        = v0;  *(f32x4*)(tp + 1024) = v1;
      *(f32x4*)(tp + 2048) = v2;  *(f32x4*)(tp + 3072) = v3;
    }
    __syncthreads();
    f32x4 r0, r1, r2, r3;
    if (wk == 0) {
      const char* tp = sm + GL_OFF + wm * 4096 + ln * 16;
      r0 = *(const f32x4*)(tp);        r1 = *(const f32x4*)(tp + 1024);
      r2 = *(const f32x4*)(tp + 2048); r3 = *(const f32x4*)(tp + 3072);
    }
    __syncthreads();   // TMP fully consumed; GL region reusable
    if (wk == 0) {
#pragma unroll
      for (int r = 0; r < 16; ++r) {
        const float add = (r < 4) ? r0[r & 3] : (r < 8) ? r1[r & 3]
                        : (r < 12) ? r2[r & 3] : r3[r & 3];
        const int rowl = wm * 32 + (r & 3) + 8 * (r >> 2) + 4 * lhi;
        GLf[rowl * 33 + l31] = acc[r] + add + wbias;   // D: col=lane&31 [m74/m101]
      }
    }
    __syncthreads();   // gates ready

    // ---- elementwise LSTM update: 2 cells per thread ----
    {
      // s = 0 : row rl
      {
        const int row = rl;
        float cold = rc0 ? 0.f : c_a;
        const float ig = GLf[row * 33 + j],      fg = GLf[row * 33 + 8 + j];
        const float gg = GLf[row * 33 + 16 + j], og = GLf[row * 33 + 24 + j];
        const float nc = sigm(fg) * cold + sigm(ig) * ftanh(gg);
        const float nh = sigm(og) * ftanh(nc);
        c_a = nc;
        out[(size_t)t * BB * HH + (size_t)row * HH + b * 8 + j] = nh;
        HNp[row * 8 + j] = rn0 ? (unsigned short)0 : f2bf(nh);
        if (t == TT - 1) {
          out[(size_t)TT * BB * HH + (size_t)row * HH + b * 8 + j] = nh;
          out[(size_t)TT * BB * HH + (size_t)BB * HH + (size_t)row * HH + b * 8 + j] = nc;
        }
      }
      // s = 1 : row rl + 64
      {
        const int row = rl + 64;
        float cold = rc1 ? 0.f : c_b;
        const float ig = GLf[row * 33 + j],      fg = GLf[row * 33 + 8 + j];
        const float gg = GLf[row * 33 + 16 + j], og = GLf[row * 33 + 24 + j];
        const float nc = sigm(fg) * cold + sigm(ig) * ftanh(gg);
        const float nh = sigm(og) * ftanh(nc);
        c_b = nc;
        out[(size_t)t * BB * HH + (size_t)row * HH + b * 8 + j] = nh;
        HNp[row * 8 + j] = rn1 ? (unsigned short)0 : f2bf(nh);
        if (t == TT - 1) {
          out[(size_t)TT * BB * HH + (size_t)row * HH + b * 8 + j] = nh;
          out[(size_t)TT * BB * HH + (size_t)BB * HH + (size_t)row * HH + b * 8 + j] = nc;
        }
      }
    }
    __syncthreads();   // HN staged

    // ---- publish h slice (coherent) + flag ----
    if (t + 1 < TT) {
      if (tid < BB) {
        const bf8 hv = *(const bf8*)(sm + HN_OFF + tid * 16);
        char* dst = (char*)hbuf + (size_t)((t + 1) & 1) * (BB * HH * 2)
                  + (size_t)tid * (HH * 2) + (size_t)b * 16;
        asm volatile("global_store_dwordx4 %0, %1, off sc0 sc1" :: "v"(dst), "v"(hv) : "memory");
      }
      asm volatile("s_waitcnt vmcnt(0)" ::: "memory");   // all waves drain their stores
      __syncthreads();
      if (tid == 0) {
        unsigned int* fp = flags + b;
        const unsigned int val = (unsigned int)(t + 2);
        asm volatile("global_store_dword %0, %1, off sc0 sc1" :: "v"(fp), "v"(val) : "memory");
      }
    }
  }
}

// ---------------- launch ----------------

extern "C" void kernel_launch(void* const* d_in, const int* in_sizes, int n_in,
                              void* d_out, int out_size, void* d_ws, size_t ws_size,
                              hipStream_t stream) {
  const float* obs  = (const float*)d_in[0];
  const void*  rst  = d_in[1];
  const float* h0   = (const float*)d_in[2];
  const float* c0   = (const float*)d_in[3];
  const float* Wx   = (const float*)d_in[4];
  const float* Wh   = (const float*)d_in[5];
  const float* bias = (const float*)d_in[6];
  float* out = (float*)d_out;

  char* ws = (char*)d_ws;
  unsigned short* Wp   = (unsigned short*)ws;                              // 16 MiB
  unsigned short* hbuf = (unsigned short*)(ws + (size_t)NG * KT * 2);      // 512 KiB (2 slots)
  unsigned int*   flags = (unsigned int*)(ws + (size_t)NG * KT * 2 + (size_t)2 * BB * HH * 2);
  int* flagmode = (int*)(flags + 256);

  const unsigned char* rB = (const unsigned char*)rst;
  const int* rI = (const int*)rst;

  k_detect<<<1, 256, 0, stream>>>((const unsigned int*)rst, flagmode, flags);
  k_pack<<<dim3((KT / 64) * (NG / 64)), dim3(256), 0, stream>>>(Wx, Wh, Wp);
  k_init<<<dim3((BB * HH) / 256), dim3(256), 0, stream>>>(h0, rB, rI, flagmode, hbuf);

  hipFuncSetAttribute((const void*)k_scan,
                      hipFuncAttributeMaxDynamicSharedMemorySize, SMEM_TOTAL);
  k_scan<<<dim3(NBLK), dim3(512), SMEM_TOTAL, stream>>>(
      obs, rB, rI, c0, bias, Wp, hbuf, flags, flagmode, out);
}

// Round 4
// 6741.438 us; speedup vs baseline: 3.7829x; 2.2193x over previous
//
#include <hip/hip_runtime.h>
#include <hip/hip_bf16.h>

// Problem dims
#define TT 512
#define BB 128
#define DD 1024
#define HH 1024
#define NG 4096    // 4*HH gate columns
#define KT 2048    // DD+HH
#define NBLK 128

using bf8    = __attribute__((ext_vector_type(8))) short;   // 8 bf16 bit patterns
using f32x4  = __attribute__((ext_vector_type(4))) float;
using f32x16 = __attribute__((ext_vector_type(16))) float;

__device__ __forceinline__ unsigned short f2bf(float f) {
  unsigned int u = __builtin_bit_cast(unsigned int, f);
  u += 0x7fffu + ((u >> 16) & 1u);   // RNE
  return (unsigned short)(u >> 16);
}
__device__ __forceinline__ float bf2f(unsigned short u) {
  unsigned int x = ((unsigned int)u) << 16;
  return __builtin_bit_cast(float, x);
}
__device__ __forceinline__ float sigm(float x) { return 1.0f / (1.0f + __expf(-x)); }
__device__ __forceinline__ float ftanh(float x) {
  float e = __expf(2.0f * x);
  return 1.0f - 2.0f / (e + 1.0f);
}

// ---------------- prep kernels ----------------

__global__ void k_detect(const unsigned int* __restrict__ rw, int* __restrict__ flagmode,
                         unsigned int* __restrict__ flags) {
  __shared__ int any;
  if (threadIdx.x == 0) any = 0;
  __syncthreads();
  int loc = 0;
  for (int i = threadIdx.x; i < (TT * BB) / 4; i += blockDim.x)
    if (rw[i] > 1u) loc = 1;
  if (loc) atomicOr(&any, 1);
  __syncthreads();
  if (threadIdx.x == 0) *flagmode = any;
  if (threadIdx.x < NBLK) flags[threadIdx.x] = 1u;
}

// Pack W = [Wx; Wh] (KT x NG, f32 row-major) into Wp[n][k] bf16 (N-major).
__global__ void k_pack(const float* __restrict__ Wx, const float* __restrict__ Wh,
                       unsigned short* __restrict__ Wp) {
  __shared__ unsigned short tile[64][65];
  const int kt = blockIdx.x & 31;
  const int nt = blockIdx.x >> 5;
  const int k0 = kt * 64, n0 = nt * 64;
  const int t = threadIdx.x;
  {
    const int kl = t >> 2;
    const int nl = (t & 3) * 16;
    const int kg = k0 + kl;
    const float* src = (kg < DD) ? (Wx + (size_t)kg * NG + n0 + nl)
                                 : (Wh + (size_t)(kg - DD) * NG + n0 + nl);
#pragma unroll
    for (int j = 0; j < 16; ++j) tile[kl][nl + j] = f2bf(src[j]);
  }
  __syncthreads();
  {
    const int nl = t >> 2;
    const int kl = (t & 3) * 16;
    unsigned short* dst = Wp + (size_t)(n0 + nl) * KT + k0 + kl;
#pragma unroll
    for (int j = 0; j < 16; ++j) dst[j] = tile[kl + j][nl];
  }
}

__global__ void k_init(const float* __restrict__ h0, const unsigned char* __restrict__ rB,
                       const int* __restrict__ rI, const int* __restrict__ flagmode,
                       unsigned short* __restrict__ hbuf) {
  const int i = blockIdx.x * 256 + threadIdx.x;
  if (i >= BB * HH) return;
  const int row = i >> 10;
  const bool r = (*flagmode) ? (rB[row] != 0) : (rI[row] != 0);
  hbuf[i] = r ? (unsigned short)0 : f2bf(h0[i]);
}

// obs f32 -> bf16
__global__ void k_cvt(const float* __restrict__ src, unsigned short* __restrict__ dst) {
  size_t i = ((size_t)blockIdx.x * 256 + threadIdx.x) * 8;
  const size_t stride = (size_t)2048 * 256 * 8;
  for (; i < (size_t)TT * BB * DD; i += stride) {
    f32x4 a = *(const f32x4*)(src + i);
    f32x4 c = *(const f32x4*)(src + i + 4);
    uint4 cv;
    asm("v_cvt_pk_bf16_f32 %0, %1, %2" : "=v"(cv.x) : "v"(a[0]), "v"(a[1]));
    asm("v_cvt_pk_bf16_f32 %0, %1, %2" : "=v"(cv.y) : "v"(a[2]), "v"(a[3]));
    asm("v_cvt_pk_bf16_f32 %0, %1, %2" : "=v"(cv.z) : "v"(c[0]), "v"(c[1]));
    asm("v_cvt_pk_bf16_f32 %0, %1, %2" : "=v"(cv.w) : "v"(c[2]), "v"(c[3]));
    *(bf8*)(dst + i) = __builtin_bit_cast(bf8, cv);
  }
}

// ---------------- gx = obs_bf @ Wx  (bf16, 128x128 tile, BK=64) ----------------
// LDS: buf0 A@0 B@16K, buf1 A@32K B@48K; epilogue Ctmp per wave @ w*17408 (aliases)
#define GEMM_SMEM 69632

__global__ void __launch_bounds__(256)
k_gemm(const unsigned short* __restrict__ A, const unsigned short* __restrict__ Bw,
       unsigned short* __restrict__ C) {
  extern __shared__ char gsm[];
  const int tid = threadIdx.x;
  const int w = tid >> 6, l = tid & 63;
  const int l15 = l & 15, lh4 = l >> 4;
  const int wm2 = w >> 1, wn2 = w & 1;
  const int mt = blockIdx.x >> 5, nt = blockIdx.x & 31;
  const size_t m0 = (size_t)mt * 128, n0 = (size_t)nt * 128;

  f32x4 acc[4][4] = {};

  const int srow = l >> 3;                 // 0..7 (row&7 for staging lane)
  const int schunk = (l & 7) ^ srow;       // pre-swizzled 16B chunk index

  const unsigned short* Ag[4];
  const unsigned short* Bg[4];
#pragma unroll
  for (int i = 0; i < 4; ++i) {
    const int r = w * 32 + i * 8 + srow;
    Ag[i] = A + (m0 + r) * 1024 + schunk * 8;
    Bg[i] = Bw + (n0 + r) * 2048 + schunk * 8;   // Wp row stride KT=2048, Wx half k<1024
  }

#define GSTAGE(BUF, KS) do {                                                        \
    const size_t ko_ = (size_t)(KS) * 64;                                           \
    char* base_ = gsm + (BUF) * 32768;                                              \
    _Pragma("unroll")                                                               \
    for (int i_ = 0; i_ < 4; ++i_) {                                                \
      __builtin_amdgcn_global_load_lds(                                             \
        (const __attribute__((address_space(1))) unsigned int*)(Ag[i_] + ko_),      \
        (__attribute__((address_space(3))) unsigned int*)(base_ + (w*32 + i_*8)*128), \
        16, 0, 0);                                                                  \
      __builtin_amdgcn_global_load_lds(                                             \
        (const __attribute__((address_space(1))) unsigned int*)(Bg[i_] + ko_),      \
        (__attribute__((address_space(3))) unsigned int*)(base_ + 16384 + (w*32 + i_*8)*128), \
        16, 0, 0);                                                                  \
    }                                                                               \
  } while (0)

#define GCOMP(BUF) do {                                                             \
    const char* bA_ = gsm + (BUF) * 32768;                                          \
    const char* bB_ = bA_ + 16384;                                                  \
    _Pragma("unroll")                                                               \
    for (int kk_ = 0; kk_ < 2; ++kk_) {                                             \
      bf8 af_[4], bf_[4];                                                           \
      _Pragma("unroll")                                                             \
      for (int mi_ = 0; mi_ < 4; ++mi_) {                                           \
        const int r_ = wm2 * 64 + mi_ * 16 + l15;                                   \
        af_[mi_] = *(const bf8*)(bA_ + r_ * 128 + ((kk_*64 + lh4*16) ^ ((r_ & 7) << 4))); \
      }                                                                             \
      _Pragma("unroll")                                                             \
      for (int ni_ = 0; ni_ < 4; ++ni_) {                                           \
        const int r_ = wn2 * 64 + ni_ * 16 + l15;                                   \
        bf_[ni_] = *(const bf8*)(bB_ + r_ * 128 + ((kk_*64 + lh4*16) ^ ((r_ & 7) << 4))); \
      }                                                                             \
      _Pragma("unroll")                                                             \
      for (int mi_ = 0; mi_ < 4; ++mi_)                                             \
        _Pragma("unroll")                                                           \
        for (int ni_ = 0; ni_ < 4; ++ni_)                                           \
          acc[mi_][ni_] = __builtin_amdgcn_mfma_f32_16x16x32_bf16(                  \
              af_[mi_], bf_[ni_], acc[mi_][ni_], 0, 0, 0);                          \
    }                                                                               \
  } while (0)

  GSTAGE(0, 0);
  asm volatile("s_waitcnt vmcnt(0)" ::: "memory");
  __syncthreads();
#pragma unroll 1
  for (int ks = 0; ks < 16; ++ks) {
    if (ks < 15) GSTAGE((ks + 1) & 1, ks + 1);
    GCOMP(ks & 1);
    if (ks < 15) {
      asm volatile("s_waitcnt vmcnt(0)" ::: "memory");
      __syncthreads();
    }
  }

  // epilogue: per-wave LDS transpose -> packed bf16 16B stores
  __syncthreads();
  float* ct = (float*)(gsm + w * 17408);   // [64][68] f32
#pragma unroll
  for (int mi = 0; mi < 4; ++mi)
#pragma unroll
    for (int ni = 0; ni < 4; ++ni)
#pragma unroll
      for (int q = 0; q < 4; ++q)
        ct[(mi * 16 + lh4 * 4 + q) * 68 + ni * 16 + l15] = acc[mi][ni][q];
  // same-wave DS ordering: no barrier needed
#pragma unroll
  for (int i = 0; i < 8; ++i) {
    const int row = i * 8 + (l >> 3);
    const int c8 = (l & 7) * 8;
    f32x4 v0 = *(const f32x4*)(ct + row * 68 + c8);
    f32x4 v1 = *(const f32x4*)(ct + row * 68 + c8 + 4);
    uint4 cv;
    asm("v_cvt_pk_bf16_f32 %0, %1, %2" : "=v"(cv.x) : "v"(v0[0]), "v"(v0[1]));
    asm("v_cvt_pk_bf16_f32 %0, %1, %2" : "=v"(cv.y) : "v"(v0[2]), "v"(v0[3]));
    asm("v_cvt_pk_bf16_f32 %0, %1, %2" : "=v"(cv.z) : "v"(v1[0]), "v"(v1[1]));
    asm("v_cvt_pk_bf16_f32 %0, %1, %2" : "=v"(cv.w) : "v"(v1[2]), "v"(v1[3]));
    *(bf8*)(C + (m0 + wm2 * 64 + row) * 4096 + n0 + wn2 * 64 + c8) =
        __builtin_bit_cast(bf8, cv);
  }
#undef GSTAGE
#undef GCOMP
}

// ---------------- serial h-scan kernel ----------------
// LDS: Wh [k8 0..127][np 0..31][16B] @0 (64K); TMP/GL @65536; GX @82432; HN @90624
#define SCANH_SMEM 92672

#define HISS(I) asm volatile("global_load_dwordx4 %0, %1, off sc0 sc1" \
    : "=v"(ha[I]) : "v"(hbB + (size_t)(I) * 64) : "memory")
#define HCON(I, VM) do { \
    asm volatile("s_waitcnt vmcnt(" #VM ")" ::: "memory"); \
    __builtin_amdgcn_sched_barrier(0); \
    const bf8 bb_ = *(const bf8*)(sm + (size_t)((I) * 4 + 2 * wk + lhi) * 512 + l31 * 16); \
    acc = __builtin_amdgcn_mfma_f32_32x32x16_bf16(ha[I], bb_, acc, 0, 0, 0); \
  } while (0)

__global__ void __launch_bounds__(512, 2)
k_scanh(const unsigned char* __restrict__ resetsB, const int* __restrict__ resetsI,
        const float* __restrict__ c0, const float* __restrict__ bias,
        const unsigned short* __restrict__ Wp, const unsigned short* __restrict__ gx,
        unsigned short* __restrict__ hbuf, unsigned int* __restrict__ flags,
        const int* __restrict__ flagmode, float* __restrict__ out) {
  extern __shared__ char sm[];
  float* GLf = (float*)(sm + 65536);
  unsigned short* HNp = (unsigned short*)(sm + 90624);

  const int tid = threadIdx.x;
  const int w   = tid >> 6;
  const int wm  = w >> 1;
  const int wk  = w & 1;
  const int ln  = tid & 63;
  const int l31 = ln & 31;
  const int lhi = ln >> 5;
  const int b   = blockIdx.x;
  const int byteMode = *flagmode;

  // ---- Wh slice -> LDS (once): k 1024..2047 of Wp rows ----
  {
    const int np = tid >> 4;          // 0..31
    const int seg = tid & 15;         // 0..15
    const int g = np >> 3, jj = np & 7;
    const unsigned short* src = Wp + (size_t)(g * 1024 + b * 8 + jj) * KT + 1024;
#pragma unroll
    for (int i = 0; i < 8; ++i) {
      const int k8 = seg * 8 + i;
      bf8 v = *(const bf8*)(src + k8 * 8);
      *(bf8*)(sm + (size_t)k8 * 512 + np * 16) = v;
    }
  }

  const int j  = tid & 7;
  const int rl = tid >> 3;            // 0..63
  float c_a = c0[(size_t)rl * HH + b * 8 + j];
  float c_b = c0[(size_t)(rl + 64) * HH + b * 8 + j];
  const float bs0 = bias[0 * HH + b * 8 + j];
  const float bs1 = bias[1 * HH + b * 8 + j];
  const float bs2 = bias[2 * HH + b * 8 + j];
  const float bs3 = bias[3 * HH + b * 8 + j];

  __syncthreads();   // Wh ready

#pragma unroll 1
  for (int t = 0; t < TT; ++t) {
    // prefetch gx chunk (16B/thread) + resets before the poll
    const bf8 gxr = *(const bf8*)(gx + ((size_t)t * BB + (tid >> 2)) * 4096
                                  + (size_t)(tid & 3) * 1024 + b * 8);
    bool rc0, rc1, rn0 = false, rn1 = false;
    if (byteMode) {
      rc0 = resetsB[t * BB + rl] != 0;  rc1 = resetsB[t * BB + rl + 64] != 0;
      if (t + 1 < TT) { rn0 = resetsB[(t+1)*BB + rl] != 0; rn1 = resetsB[(t+1)*BB + rl + 64] != 0; }
    } else {
      rc0 = resetsI[t * BB + rl] != 0;  rc1 = resetsI[t * BB + rl + 64] != 0;
      if (t + 1 < TT) { rn0 = resetsI[(t+1)*BB + rl] != 0; rn1 = resetsI[(t+1)*BB + rl + 64] != 0; }
    }

    // ---- poll producer flags ----
    {
      const unsigned long long* f64 = (const unsigned long long*)flags;
      const unsigned int need = (unsigned int)(t + 1);
      while (true) {
        unsigned long long v = __hip_atomic_load(&f64[ln], __ATOMIC_RELAXED,
                                                 __HIP_MEMORY_SCOPE_AGENT);
        const int ok = ((unsigned int)v >= need) && ((unsigned int)(v >> 32) >= need);
        if (__all(ok)) break;
        __builtin_amdgcn_s_sleep(2);
      }
    }
    asm volatile("s_waitcnt vmcnt(0)" ::: "memory");
    __builtin_amdgcn_sched_barrier(0);

    // stage gx into LDS (read after reduce barriers)
    *(bf8*)(sm + 82432 + (size_t)tid * 16) = gxr;

    // ---- h phase: issue all 32 coherent loads, counted-vmcnt drain ----
    f32x16 acc = {0.f,0.f,0.f,0.f, 0.f,0.f,0.f,0.f, 0.f,0.f,0.f,0.f, 0.f,0.f,0.f,0.f};
    {
      const char* hbB = (const char*)hbuf + (size_t)(t & 1) * (BB * HH * 2)
                      + (size_t)(wm * 32 + l31) * (HH * 2) + (size_t)wk * 32 + (size_t)lhi * 16;
      bf8 ha[32];
      HISS(0);  HISS(1);  HISS(2);  HISS(3);  HISS(4);  HISS(5);  HISS(6);  HISS(7);
      HISS(8);  HISS(9);  HISS(10); HISS(11); HISS(12); HISS(13); HISS(14); HISS(15);
      HISS(16); HISS(17); HISS(18); HISS(19); HISS(20); HISS(21); HISS(22); HISS(23);
      HISS(24); HISS(25); HISS(26); HISS(27); HISS(28); HISS(29); HISS(30); HISS(31);
      HCON(0, 31);  HCON(1, 30);  HCON(2, 29);  HCON(3, 28);
      HCON(4, 27);  HCON(5, 26);  HCON(6, 25);  HCON(7, 24);
      HCON(8, 23);  HCON(9, 22);  HCON(10, 21); HCON(11, 20);
      HCON(12, 19); HCON(13, 18); HCON(14, 17); HCON(15, 16);
      HCON(16, 15); HCON(17, 14); HCON(18, 13); HCON(19, 12);
      HCON(20, 11); HCON(21, 10); HCON(22, 9);  HCON(23, 8);
      HCON(24, 7);  HCON(25, 6);  HCON(26, 5);  HCON(27, 4);
      HCON(28, 3);  HCON(29, 2);  HCON(30, 1);  HCON(31, 0);
    }

    // ---- K-split reduce (TMP aliases GL region) ----
    if (wk == 1) {
      char* tp = sm + 65536 + wm * 4096 + ln * 16;
      f32x4 v0 = {acc[0], acc[1], acc[2], acc[3]};
      f32x4 v1 = {acc[4], acc[5], acc[6], acc[7]};
      f32x4 v2 = {acc[8], acc[9], acc[10], acc[11]};
      f32x4 v3 = {acc[12], acc[13], acc[14], acc[15]};
      *(f32x4*)(tp)        = v0;  *(f32x4*)(tp + 1024) = v1;
      *(f32x4*)(tp + 2048) = v2;  *(f32x4*)(tp + 3072) = v3;
    }
    __syncthreads();
    f32x4 r0, r1, r2, r3;
    if (wk == 0) {
      const char* tp = sm + 65536 + wm * 4096 + ln * 16;
      r0 = *(const f32x4*)(tp);        r1 = *(const f32x4*)(tp + 1024);
      r2 = *(const f32x4*)(tp + 2048); r3 = *(const f32x4*)(tp + 3072);
    }
    __syncthreads();
    if (wk == 0) {
#pragma unroll
      for (int r = 0; r < 16; ++r) {
        const float add = (r < 4) ? r0[r & 3] : (r < 8) ? r1[r & 3]
                        : (r < 12) ? r2[r & 3] : r3[r & 3];
        const int rowl = wm * 32 + (r & 3) + 8 * (r >> 2) + 4 * lhi;
        GLf[rowl * 33 + l31] = acc[r] + add;   // h-part only; gx+bias at elementwise
      }
    }
    __syncthreads();   // gates + GX visible

    // ---- elementwise LSTM ----
    {
      const unsigned short* GXp = (const unsigned short*)(sm + 82432);
      {
        const int row = rl;
        float cold = rc0 ? 0.f : c_a;
        const float ig = GLf[row*33 +      j] + bf2f(GXp[(row*4+0)*8 + j]) + bs0;
        const float fg = GLf[row*33 +  8 + j] + bf2f(GXp[(row*4+1)*8 + j]) + bs1;
        const float gg = GLf[row*33 + 16 + j] + bf2f(GXp[(row*4+2)*8 + j]) + bs2;
        const float og = GLf[row*33 + 24 + j] + bf2f(GXp[(row*4+3)*8 + j]) + bs3;
        const float nc = sigm(fg) * cold + sigm(ig) * ftanh(gg);
        const float nh = sigm(og) * ftanh(nc);
        c_a = nc;
        out[(size_t)t * BB * HH + (size_t)row * HH + b * 8 + j] = nh;
        HNp[row * 8 + j] = rn0 ? (unsigned short)0 : f2bf(nh);
        if (t == TT - 1) {
          out[(size_t)TT * BB * HH + (size_t)row * HH + b * 8 + j] = nh;
          out[(size_t)TT * BB * HH + (size_t)BB * HH + (size_t)row * HH + b * 8 + j] = nc;
        }
      }
      {
        const int row = rl + 64;
        float cold = rc1 ? 0.f : c_b;
        const float ig = GLf[row*33 +      j] + bf2f(GXp[(row*4+0)*8 + j]) + bs0;
        const float fg = GLf[row*33 +  8 + j] + bf2f(GXp[(row*4+1)*8 + j]) + bs1;
        const float gg = GLf[row*33 + 16 + j] + bf2f(GXp[(row*4+2)*8 + j]) + bs2;
        const float og = GLf[row*33 + 24 + j] + bf2f(GXp[(row*4+3)*8 + j]) + bs3;
        const float nc = sigm(fg) * cold + sigm(ig) * ftanh(gg);
        const float nh = sigm(og) * ftanh(nc);
        c_b = nc;
        out[(size_t)t * BB * HH + (size_t)row * HH + b * 8 + j] = nh;
        HNp[row * 8 + j] = rn1 ? (unsigned short)0 : f2bf(nh);
        if (t == TT - 1) {
          out[(size_t)TT * BB * HH + (size_t)row * HH + b * 8 + j] = nh;
          out[(size_t)TT * BB * HH + (size_t)BB * HH + (size_t)row * HH + b * 8 + j] = nc;
        }
      }
    }
    __syncthreads();   // HN staged

    // ---- publish ----
    if (t + 1 < TT) {
      if (tid < BB) {
        const bf8 hv = *(const bf8*)(sm + 90624 + tid * 16);
        char* dst = (char*)hbuf + (size_t)((t + 1) & 1) * (BB * HH * 2)
                  + (size_t)tid * (HH * 2) + (size_t)b * 16;
        asm volatile("global_store_dwordx4 %0, %1, off sc0 sc1" :: "v"(dst), "v"(hv) : "memory");
      }
      asm volatile("s_waitcnt vmcnt(0)" ::: "memory");
      __syncthreads();
      if (tid == 0) {
        unsigned int* fp = flags + b;
        const unsigned int val = (unsigned int)(t + 2);
        asm volatile("global_store_dword %0, %1, off sc0 sc1" :: "v"(fp), "v"(val) : "memory");
      }
    }
  }
}

// ---------------- fallback (round-3 kernel, ws too small) ----------------
#define FB_GL_OFF 131072
#define FB_HN_OFF 147968
#define FB_SMEM   150016

#define FB_HLD(dst, KH) asm volatile("global_load_dwordx4 %0, %1, off sc0 sc1" \
    : "=v"(dst) : "v"(hbB + (size_t)(KH) * 64) : "memory")
#define FB_HSTEP(IT, WCA, WCB) do {                                                  \
  asm volatile("s_waitcnt vmcnt(" WCA ")" ::: "memory");                             \
  __builtin_amdgcn_sched_barrier(0);                                                 \
  { const bf8 bbA = *(const bf8*)(sm + (size_t)(128 + 8*(IT) + 2*wk + lhi)*512 + l31*16); \
    acc = __builtin_amdgcn_mfma_f32_32x32x16_bf16(hA, bbA, acc, 0, 0, 0); }          \
  if ((IT) < 15) FB_HLD(hA, 2*(IT) + 2);                                             \
  asm volatile("s_waitcnt vmcnt(" WCB ")" ::: "memory");                             \
  __builtin_amdgcn_sched_barrier(0);                                                 \
  { const bf8 bbB = *(const bf8*)(sm + (size_t)(128 + 8*(IT) + 4 + 2*wk + lhi)*512 + l31*16); \
    acc = __builtin_amdgcn_mfma_f32_32x32x16_bf16(hB, bbB, acc, 0, 0, 0); }          \
  if ((IT) < 15) FB_HLD(hB, 2*(IT) + 3);                                             \
} while (0)

__global__ void __launch_bounds__(512)
k_scan_fb(const float* __restrict__ obs, const unsigned char* __restrict__ resetsB,
          const int* __restrict__ resetsI, const float* __restrict__ c0,
          const float* __restrict__ bias, const unsigned short* __restrict__ Wp,
          unsigned short* __restrict__ hbuf, unsigned int* __restrict__ flags,
          const int* __restrict__ flagmode, float* __restrict__ out) {
  extern __shared__ char sm[];
  float* GLf = (float*)(sm + FB_GL_OFF);
  unsigned short* HNp = (unsigned short*)(sm + FB_HN_OFF);

  const int tid = threadIdx.x;
  const int w   = tid >> 6;
  const int wm  = w >> 1;
  const int wk  = w & 1;
  const int ln  = tid & 63;
  const int l31 = ln & 31;
  const int lhi = ln >> 5;
  const int b   = blockIdx.x;
  const int byteMode = *flagmode;

  {
    const int np_ld = tid >> 4;
    const int seg   = tid & 15;
    const int g = np_ld >> 3, jj = np_ld & 7;
    const unsigned short* src = Wp + (size_t)(g * 1024 + b * 8 + jj) * KT;
#pragma unroll 4
    for (int i = 0; i < 16; ++i) {
      const int k8 = seg * 16 + i;
      bf8 v = *(const bf8*)(src + k8 * 8);
      *(bf8*)(sm + (size_t)k8 * 512 + np_ld * 16) = v;
    }
  }

  const int j  = tid & 7;
  const int rl = tid >> 3;
  float c_a = c0[(size_t)rl * HH + b * 8 + j];
  float c_b = c0[(size_t)(rl + 64) * HH + b * 8 + j];
  const float wbias = bias[(l31 >> 3) * 1024 + b * 8 + (l31 & 7)];

  __syncthreads();

#pragma unroll 1
  for (int t = 0; t < TT; ++t) {
    bool rc0, rc1, rn0 = false, rn1 = false;
    if (byteMode) {
      rc0 = resetsB[t * BB + rl] != 0;  rc1 = resetsB[t * BB + rl + 64] != 0;
      if (t + 1 < TT) { rn0 = resetsB[(t+1)*BB + rl] != 0; rn1 = resetsB[(t+1)*BB + rl + 64] != 0; }
    } else {
      rc0 = resetsI[t * BB + rl] != 0;  rc1 = resetsI[t * BB + rl + 64] != 0;
      if (t + 1 < TT) { rn0 = resetsI[(t+1)*BB + rl] != 0; rn1 = resetsI[(t+1)*BB + rl + 64] != 0; }
    }

    f32x16 acc = {0.f,0.f,0.f,0.f, 0.f,0.f,0.f,0.f, 0.f,0.f,0.f,0.f, 0.f,0.f,0.f,0.f};

    {
      const float* xbase = obs + ((size_t)t * BB + wm * 32 + l31) * DD + wk * 16 + lhi * 8;
#pragma unroll 8
      for (int ks = 0; ks < 32; ++ks) {
        const float* xp = xbase + ks * 32;
        f32x4 f0 = *(const f32x4*)xp;
        f32x4 f1 = *(const f32x4*)(xp + 4);
        uint4 cv;
        asm("v_cvt_pk_bf16_f32 %0, %1, %2" : "=v"(cv.x) : "v"(f0[0]), "v"(f0[1]));
        asm("v_cvt_pk_bf16_f32 %0, %1, %2" : "=v"(cv.y) : "v"(f0[2]), "v"(f0[3]));
        asm("v_cvt_pk_bf16_f32 %0, %1, %2" : "=v"(cv.z) : "v"(f1[0]), "v"(f1[1]));
        asm("v_cvt_pk_bf16_f32 %0, %1, %2" : "=v"(cv.w) : "v"(f1[2]), "v"(f1[3]));
        const bf8 xa = __builtin_bit_cast(bf8, cv);
        const bf8 xb = *(const bf8*)(sm + (size_t)(4 * ks + 2 * wk + lhi) * 512 + l31 * 16);
        acc = __builtin_amdgcn_mfma_f32_32x32x16_bf16(xa, xb, acc, 0, 0, 0);
      }
    }

    {
      const unsigned long long* f64 = (const unsigned long long*)flags;
      const unsigned int need = (unsigned int)(t + 1);
      while (true) {
        unsigned long long v = __hip_atomic_load(&f64[ln], __ATOMIC_RELAXED,
                                                 __HIP_MEMORY_SCOPE_AGENT);
        const int ok = ((unsigned int)v >= need) && ((unsigned int)(v >> 32) >= need);
        if (__all(ok)) break;
        __builtin_amdgcn_s_sleep(2);
      }
    }
    asm volatile("s_waitcnt vmcnt(0)" ::: "memory");
    __builtin_amdgcn_sched_barrier(0);

    {
      const char* hbB = (const char*)hbuf + (size_t)(t & 1) * (BB * HH * 2)
                      + (size_t)(wm * 32 + l31) * (HH * 2) + (size_t)wk * 32 + (size_t)lhi * 16;
      bf8 hA, hB;
      FB_HLD(hA, 0); FB_HLD(hB, 1);
      FB_HSTEP(0,  "1", "1");  FB_HSTEP(1,  "1", "1");  FB_HSTEP(2,  "1", "1");
      FB_HSTEP(3,  "1", "1");  FB_HSTEP(4,  "1", "1");  FB_HSTEP(5,  "1", "1");
      FB_HSTEP(6,  "1", "1");  FB_HSTEP(7,  "1", "1");  FB_HSTEP(8,  "1", "1");
      FB_HSTEP(9,  "1", "1");  FB_HSTEP(10, "1", "1");  FB_HSTEP(11, "1", "1");
      FB_HSTEP(12, "1", "1");  FB_HSTEP(13, "1", "1");  FB_HSTEP(14, "1", "1");
      FB_HSTEP(15, "1", "0");
    }

    if (wk == 1) {
      char* tp = sm + FB_GL_OFF + wm * 4096 + ln * 16;
      f32x4 v0 = {acc[0], acc[1], acc[2], acc[3]};
      f32x4 v1 = {acc[4], acc[5], acc[6], acc[7]};
      f32x4 v2 = {acc[8], acc[9], acc[10], acc[11]};
      f32x4 v3 = {acc[12], acc[13], acc[14], acc[15]};
      *(f32x4*)(tp)        = v0;  *(f32x4*)(tp + 1024) = v1;
      *(f32x4*)(tp + 2048) = v2;  *(f32x4*)(tp + 3072) = v3;
    }
    __syncthreads();
    f32x4 r0, r1, r2, r3;
    if (wk == 0) {
      const char* tp = sm + FB_GL_OFF + wm * 4096 + ln * 16;
      r0 = *(const f32x4*)(tp);        r1 = *(const f32x4*)(tp + 1024);
      r2 = *(const f32x4*)(tp + 2048); r3 = *(const f32x4*)(tp + 3072);
    }
    __syncthreads();
    if (wk == 0) {
#pragma unroll
      for (int r = 0; r < 16; ++r) {
        const float add = (r < 4) ? r0[r & 3] : (r < 8) ? r1[r & 3]
                        : (r < 12) ? r2[r & 3] : r3[r & 3];
        const int rowl = wm * 32 + (r & 3) + 8 * (r >> 2) + 4 * lhi;
        GLf[rowl * 33 + l31] = acc[r] + add + wbias;
      }
    }
    __syncthreads();

    {
      {
        const int row = rl;
        float cold = rc0 ? 0.f : c_a;
        const float ig = GLf[row * 33 + j],      fg = GLf[row * 33 + 8 + j];
        const float gg = GLf[row * 33 + 16 + j], og = GLf[row * 33 + 24 + j];
        const float nc = sigm(fg) * cold + sigm(ig) * ftanh(gg);
        const float nh = sigm(og) * ftanh(nc);
        c_a = nc;
        out[(size_t)t * BB * HH + (size_t)row * HH + b * 8 + j] = nh;
        HNp[row * 8 + j] = rn0 ? (unsigned short)0 : f2bf(nh);
        if (t == TT - 1) {
          out[(size_t)TT * BB * HH + (size_t)row * HH + b * 8 + j] = nh;
          out[(size_t)TT * BB * HH + (size_t)BB * HH + (size_t)row * HH + b * 8 + j] = nc;
        }
      }
      {
        const int row = rl + 64;
        float cold = rc1 ? 0.f : c_b;
        const float ig = GLf[row * 33 + j],      fg = GLf[row * 33 + 8 + j];
        const float gg = GLf[row * 33 + 16 + j], og = GLf[row * 33 + 24 + j];
        const float nc = sigm(fg) * cold + sigm(ig) * ftanh(gg);
        const float nh = sigm(og) * ftanh(nc);
        c_b = nc;
        out[(size_t)t * BB * HH + (size_t)row * HH + b * 8 + j] = nh;
        HNp[row * 8 + j] = rn1 ? (unsigned short)0 : f2bf(nh);
        if (t == TT - 1) {
          out[(size_t)TT * BB * HH + (size_t)row * HH + b * 8 + j] = nh;
          out[(size_t)TT * BB * HH + (size_t)BB * HH + (size_t)row * HH + b * 8 + j] = nc;
        }
      }
    }
    __syncthreads();

    if (t + 1 < TT) {
      if (tid < BB) {
        const bf8 hv = *(const bf8*)(sm + FB_HN_OFF + tid * 16);
        char* dst = (char*)hbuf + (size_t)((t + 1) & 1) * (BB * HH * 2)
                  + (size_t)tid * (HH * 2) + (size_t)b * 16;
        asm volatile("global_store_dwordx4 %0, %1, off sc0 sc1" :: "v"(dst), "v"(hv) : "memory");
      }
      asm volatile("s_waitcnt vmcnt(0)" ::: "memory");
      __syncthreads();
      if (tid == 0) {
        unsigned int* fp = flags + b;
        const unsigned int val = (unsigned int)(t + 2);
        asm volatile("global_store_dword %0, %1, off sc0 sc1" :: "v"(fp), "v"(val) : "memory");
      }
    }
  }
}

// ---------------- launch ----------------

extern "C" void kernel_launch(void* const* d_in, const int* in_sizes, int n_in,
                              void* d_out, int out_size, void* d_ws, size_t ws_size,
                              hipStream_t stream) {
  const float* obs  = (const float*)d_in[0];
  const void*  rst  = d_in[1];
  const float* h0   = (const float*)d_in[2];
  const float* c0   = (const float*)d_in[3];
  const float* Wx   = (const float*)d_in[4];
  const float* Wh   = (const float*)d_in[5];
  const float* bias = (const float*)d_in[6];
  float* out = (float*)d_out;

  char* ws = (char*)d_ws;
  const size_t WP_OFF    = 0;                                   // 16 MiB
  const size_t HBUF_OFF  = (size_t)16 << 20;                    // 0.5 MiB
  const size_t FLAGS_OFF = HBUF_OFF + ((size_t)512 << 10);
  const size_t OBSBF_OFF = (size_t)24 << 20;                    // 128 MiB
  const size_t GX_OFF    = OBSBF_OFF + ((size_t)128 << 20);     // 512 MiB
  const size_t WS_NEED   = GX_OFF + (size_t)TT * BB * NG * 2;

  unsigned short* Wp    = (unsigned short*)(ws + WP_OFF);
  unsigned short* hbuf  = (unsigned short*)(ws + HBUF_OFF);
  unsigned int*   flags = (unsigned int*)(ws + FLAGS_OFF);
  int*        flagmode  = (int*)(flags + 256);
  unsigned short* obsbf = (unsigned short*)(ws + OBSBF_OFF);
  unsigned short* gxp   = (unsigned short*)(ws + GX_OFF);

  const unsigned char* rB = (const unsigned char*)rst;
  const int* rI = (const int*)rst;

  k_detect<<<1, 256, 0, stream>>>((const unsigned int*)rst, flagmode, flags);
  k_pack<<<dim3((KT / 64) * (NG / 64)), dim3(256), 0, stream>>>(Wx, Wh, Wp);
  k_init<<<dim3((BB * HH) / 256), dim3(256), 0, stream>>>(h0, rB, rI, flagmode, hbuf);

  if (ws_size >= WS_NEED) {
    k_cvt<<<dim3(2048), dim3(256), 0, stream>>>(obs, obsbf);
    hipFuncSetAttribute((const void*)k_gemm,
                        hipFuncAttributeMaxDynamicSharedMemorySize, GEMM_SMEM);
    k_gemm<<<dim3((TT * BB / 128) * (NG / 128)), dim3(256), GEMM_SMEM, stream>>>(
        obsbf, Wp, gxp);
    hipFuncSetAttribute((const void*)k_scanh,
                        hipFuncAttributeMaxDynamicSharedMemorySize, SCANH_SMEM);
    k_scanh<<<dim3(NBLK), dim3(512), SCANH_SMEM, stream>>>(
        rB, rI, c0, bias, Wp, gxp, hbuf, flags, flagmode, out);
  } else {
    hipFuncSetAttribute((const void*)k_scan_fb,
                        hipFuncAttributeMaxDynamicSharedMemorySize, FB_SMEM);
    k_scan_fb<<<dim3(NBLK), dim3(512), FB_SMEM, stream>>>(
        obs, rB, rI, c0, bias, Wp, hbuf, flags, flagmode, out);
  }
}

// Round 7
// 3332.354 us; speedup vs baseline: 7.6529x; 2.0230x over previous
//
#include <hip/hip_runtime.h>
#include <hip/hip_bf16.h>

// Problem dims
#define TT 512
#define BB 128
#define DD 1024
#define HH 1024
#define NG 4096    // 4*HH gate columns
#define KT 2048    // DD+HH
#define NBLK 128

using bf8    = __attribute__((ext_vector_type(8))) short;   // 8 bf16 bit patterns
using f32x4  = __attribute__((ext_vector_type(4))) float;
using f32x16 = __attribute__((ext_vector_type(16))) float;

__device__ __forceinline__ unsigned short f2bf(float f) {
  unsigned int u = __builtin_bit_cast(unsigned int, f);
  u += 0x7fffu + ((u >> 16) & 1u);   // RNE
  return (unsigned short)(u >> 16);
}
__device__ __forceinline__ float bf2f(unsigned short u) {
  unsigned int x = ((unsigned int)u) << 16;
  return __builtin_bit_cast(float, x);
}
__device__ __forceinline__ float sigm(float x) { return 1.0f / (1.0f + __expf(-x)); }
__device__ __forceinline__ float ftanh(float x) {
  float e = __expf(2.0f * x);
  return 1.0f - 2.0f / (e + 1.0f);
}

// ---------------- prep kernels ----------------

__global__ void k_detect(const unsigned int* __restrict__ rw, int* __restrict__ flagmode,
                         unsigned int* __restrict__ flags) {
  __shared__ int any;
  if (threadIdx.x == 0) any = 0;
  __syncthreads();
  int loc = 0;
  for (int i = threadIdx.x; i < (TT * BB) / 4; i += blockDim.x)
    if (rw[i] > 1u) loc = 1;
  if (loc) atomicOr(&any, 1);
  __syncthreads();
  if (threadIdx.x == 0) *flagmode = any;
  if (threadIdx.x < NBLK) flags[threadIdx.x] = 1u;   // h-input for step 0 ready
}

// Pack W = [Wx; Wh] (KT x NG, f32 row-major) into Wp[n][k] bf16 (N-major).
__global__ void k_pack(const float* __restrict__ Wx, const float* __restrict__ Wh,
                       unsigned short* __restrict__ Wp) {
  __shared__ unsigned short tile[64][65];
  const int kt = blockIdx.x & 31;
  const int nt = blockIdx.x >> 5;
  const int k0 = kt * 64, n0 = nt * 64;
  const int t = threadIdx.x;
  {
    const int kl = t >> 2;
    const int nl = (t & 3) * 16;
    const int kg = k0 + kl;
    const float* src = (kg < DD) ? (Wx + (size_t)kg * NG + n0 + nl)
                                 : (Wh + (size_t)(kg - DD) * NG + n0 + nl);
#pragma unroll
    for (int j = 0; j < 16; ++j) tile[kl][nl + j] = f2bf(src[j]);
  }
  __syncthreads();
  {
    const int nl = t >> 2;
    const int kl = (t & 3) * 16;
    unsigned short* dst = Wp + (size_t)(n0 + nl) * KT + k0 + kl;
#pragma unroll
    for (int j = 0; j < 16; ++j) dst[j] = tile[kl + j][nl];
  }
}

// old-layout hbuf init (fallback path)
__global__ void k_init(const float* __restrict__ h0, const unsigned char* __restrict__ rB,
                       const int* __restrict__ rI, const int* __restrict__ flagmode,
                       unsigned short* __restrict__ hbuf) {
  const int i = blockIdx.x * 256 + threadIdx.x;
  if (i >= BB * HH) return;
  const int row = i >> 10;
  const bool r = (*flagmode) ? (rB[row] != 0) : (rI[row] != 0);
  hbuf[i] = r ? (unsigned short)0 : f2bf(h0[i]);
}

// staged-layout hbufB init: hbufB[slot0][rt][k8][r32][8]
__global__ void k_initB(const float* __restrict__ h0, const unsigned char* __restrict__ rB,
                        const int* __restrict__ rI, const int* __restrict__ flagmode,
                        unsigned short* __restrict__ hbufB) {
  const int i = blockIdx.x * 256 + threadIdx.x;
  if (i >= BB * HH) return;
  const int row = i >> 10, hcol = i & 1023;
  const bool r = (*flagmode) ? (rB[row] != 0) : (rI[row] != 0);
  const unsigned short val = r ? (unsigned short)0 : f2bf(h0[i]);
  const size_t e = ((size_t)(row >> 5) * 128 + (hcol >> 3)) * 256 + (row & 31) * 8 + (hcol & 7);
  hbufB[e] = val;
}

// obs f32 -> bf16
__global__ void k_cvt(const float* __restrict__ src, unsigned short* __restrict__ dst) {
  size_t i = ((size_t)blockIdx.x * 256 + threadIdx.x) * 8;
  const size_t stride = (size_t)2048 * 256 * 8;
  for (; i < (size_t)TT * BB * DD; i += stride) {
    f32x4 a = *(const f32x4*)(src + i);
    f32x4 c = *(const f32x4*)(src + i + 4);
    uint4 cv;
    asm("v_cvt_pk_bf16_f32 %0, %1, %2" : "=v"(cv.x) : "v"(a[0]), "v"(a[1]));
    asm("v_cvt_pk_bf16_f32 %0, %1, %2" : "=v"(cv.y) : "v"(a[2]), "v"(a[3]));
    asm("v_cvt_pk_bf16_f32 %0, %1, %2" : "=v"(cv.z) : "v"(c[0]), "v"(c[1]));
    asm("v_cvt_pk_bf16_f32 %0, %1, %2" : "=v"(cv.w) : "v"(c[2]), "v"(c[3]));
    *(bf8*)(dst + i) = __builtin_bit_cast(bf8, cv);
  }
}

// ---------------- gx = obs_bf @ Wx  (bf16, 128x128 tile, BK=64) ----------------
#define GEMM_SMEM 69632

__global__ void __launch_bounds__(256)
k_gemm(const unsigned short* __restrict__ A, const unsigned short* __restrict__ Bw,
       unsigned short* __restrict__ C) {
  extern __shared__ char gsm[];
  const int tid = threadIdx.x;
  const int w = tid >> 6, l = tid & 63;
  const int l15 = l & 15, lh4 = l >> 4;
  const int wm2 = w >> 1, wn2 = w & 1;
  const int mt = blockIdx.x >> 5, nt = blockIdx.x & 31;
  const size_t m0 = (size_t)mt * 128, n0 = (size_t)nt * 128;

  f32x4 acc[4][4] = {};

  const int srow = l >> 3;
  const int schunk = (l & 7) ^ srow;

  const unsigned short* Ag[4];
  const unsigned short* Bg[4];
#pragma unroll
  for (int i = 0; i < 4; ++i) {
    const int r = w * 32 + i * 8 + srow;
    Ag[i] = A + (m0 + r) * 1024 + schunk * 8;
    Bg[i] = Bw + (n0 + r) * 2048 + schunk * 8;
  }

#define GSTAGE(BUF, KS) do {                                                        \
    const size_t ko_ = (size_t)(KS) * 64;                                           \
    char* base_ = gsm + (BUF) * 32768;                                              \
    _Pragma("unroll")                                                               \
    for (int i_ = 0; i_ < 4; ++i_) {                                                \
      __builtin_amdgcn_global_load_lds(                                             \
        (const __attribute__((address_space(1))) unsigned int*)(Ag[i_] + ko_),      \
        (__attribute__((address_space(3))) unsigned int*)(base_ + (w*32 + i_*8)*128), \
        16, 0, 0);                                                                  \
      __builtin_amdgcn_global_load_lds(                                             \
        (const __attribute__((address_space(1))) unsigned int*)(Bg[i_] + ko_),      \
        (__attribute__((address_space(3))) unsigned int*)(base_ + 16384 + (w*32 + i_*8)*128), \
        16, 0, 0);                                                                  \
    }                                                                               \
  } while (0)

#define GCOMP(BUF) do {                                                             \
    const char* bA_ = gsm + (BUF) * 32768;                                          \
    const char* bB_ = bA_ + 16384;                                                  \
    _Pragma("unroll")                                                               \
    for (int kk_ = 0; kk_ < 2; ++kk_) {                                             \
      bf8 af_[4], bf_[4];                                                           \
      _Pragma("unroll")                                                             \
      for (int mi_ = 0; mi_ < 4; ++mi_) {                                           \
        const int r_ = wm2 * 64 + mi_ * 16 + l15;                                   \
        af_[mi_] = *(const bf8*)(bA_ + r_ * 128 + ((kk_*64 + lh4*16) ^ ((r_ & 7) << 4))); \
      }                                                                             \
      _Pragma("unroll")                                                             \
      for (int ni_ = 0; ni_ < 4; ++ni_) {                                           \
        const int r_ = wn2 * 64 + ni_ * 16 + l15;                                   \
        bf_[ni_] = *(const bf8*)(bB_ + r_ * 128 + ((kk_*64 + lh4*16) ^ ((r_ & 7) << 4))); \
      }                                                                             \
      _Pragma("unroll")                                                             \
      for (int mi_ = 0; mi_ < 4; ++mi_)                                             \
        _Pragma("unroll")                                                           \
        for (int ni_ = 0; ni_ < 4; ++ni_)                                           \
          acc[mi_][ni_] = __builtin_amdgcn_mfma_f32_16x16x32_bf16(                  \
              af_[mi_], bf_[ni_], acc[mi_][ni_], 0, 0, 0);                          \
    }                                                                               \
  } while (0)

  GSTAGE(0, 0);
  asm volatile("s_waitcnt vmcnt(0)" ::: "memory");
  __syncthreads();
#pragma unroll 1
  for (int ks = 0; ks < 16; ++ks) {
    if (ks < 15) GSTAGE((ks + 1) & 1, ks + 1);
    GCOMP(ks & 1);
    if (ks < 15) {
      asm volatile("s_waitcnt vmcnt(0)" ::: "memory");
      __syncthreads();
    }
  }

  __syncthreads();
  float* ct = (float*)(gsm + w * 17408);   // [64][68] f32
#pragma unroll
  for (int mi = 0; mi < 4; ++mi)
#pragma unroll
    for (int ni = 0; ni < 4; ++ni)
#pragma unroll
      for (int q = 0; q < 4; ++q)
        ct[(mi * 16 + lh4 * 4 + q) * 68 + ni * 16 + l15] = acc[mi][ni][q];
#pragma unroll
  for (int i = 0; i < 8; ++i) {
    const int row = i * 8 + (l >> 3);
    const int c8 = (l & 7) * 8;
    f32x4 v0 = *(const f32x4*)(ct + row * 68 + c8);
    f32x4 v1 = *(const f32x4*)(ct + row * 68 + c8 + 4);
    uint4 cv;
    asm("v_cvt_pk_bf16_f32 %0, %1, %2" : "=v"(cv.x) : "v"(v0[0]), "v"(v0[1]));
    asm("v_cvt_pk_bf16_f32 %0, %1, %2" : "=v"(cv.y) : "v"(v0[2]), "v"(v0[3]));
    asm("v_cvt_pk_bf16_f32 %0, %1, %2" : "=v"(cv.z) : "v"(v1[0]), "v"(v1[1]));
    asm("v_cvt_pk_bf16_f32 %0, %1, %2" : "=v"(cv.w) : "v"(v1[2]), "v"(v1[3]));
    *(bf8*)(C + (m0 + wm2 * 64 + row) * 4096 + n0 + wn2 * 64 + c8) =
        __builtin_bit_cast(bf8, cv);
  }
#undef GSTAGE
#undef GCOMP
}

// ---------------- serial h-scan kernel v2: 2 batch groups x 64 blocks ----------------
// LDS: Wh [k8 0..127][c 0..63][16B] @0 (131072); TMP/GL alias @131072 (16384)
#define SCANH2_SMEM 147456
#define HSLOT 262144   // bytes per hbufB slot

#define HI(I) asm volatile("global_load_dwordx4 %0, %1, off sc0 sc1" \
    : "=v"(ha[I]) : "v"(hbB + (I) * 1024 + lhi * 512) : "memory")

#define BRD(CI, N2) (*(const bf8*)(sm + \
    (size_t)(((wn * 64 + (CI) * 2 + lhi) * 64 + (N2) * 32 + l31)) * 16))

#define HC(CI, VM) do {                                                  \
    bf8 nb0, nb1;                                                        \
    if ((CI) < 31) { nb0 = BRD((CI) + 1, 0); nb1 = BRD((CI) + 1, 1); }   \
    asm volatile("s_waitcnt vmcnt(" #VM ")" ::: "memory");               \
    __builtin_amdgcn_sched_barrier(0);                                   \
    ac0 = __builtin_amdgcn_mfma_f32_32x32x16_bf16(ha[CI], cb0, ac0, 0, 0, 0); \
    ac1 = __builtin_amdgcn_mfma_f32_32x32x16_bf16(ha[CI], cb1, ac1, 0, 0, 0); \
    cb0 = nb0; cb1 = nb1;                                                \
  } while (0)

__global__ void __launch_bounds__(256)
k_scanh2(const unsigned char* __restrict__ resetsB, const int* __restrict__ resetsI,
         const float* __restrict__ c0, const float* __restrict__ bias,
         const unsigned short* __restrict__ Wp, const unsigned short* __restrict__ gx,
         unsigned short* __restrict__ hbufB, unsigned int* __restrict__ flags,
         const int* __restrict__ flagmode, float* __restrict__ out) {
  extern __shared__ char sm[];
  float* TG = (float*)(sm + 131072);   // TMP then GL (aliased)

  const int tid = threadIdx.x;
  const int w   = tid >> 6;
  const int wm  = w >> 1;        // row half within group (32 rows)
  const int wn  = w & 1;         // K half
  const int ln  = tid & 63;
  const int l31 = ln & 31;
  const int lhi = ln >> 5;
  const int bid = blockIdx.x;
  const int g   = bid >> 6;      // batch group 0/1
  const int b   = bid & 63;      // 16 h-cols per block
  const int byteMode = *flagmode;

  // ---- Wh slice -> LDS (once): [k8][c][8], c = gate*16 + hcloc ----
  {
    const int c = tid >> 2, seg = tid & 3;
    const int n = (c >> 4) * 1024 + b * 16 + (c & 15);
    const unsigned short* src = Wp + (size_t)n * KT + 1024;
#pragma unroll 8
    for (int i = 0; i < 32; ++i) {
      const int k8 = seg * 32 + i;
      bf8 v = *(const bf8*)(src + k8 * 8);
      *(bf8*)(sm + ((size_t)k8 * 64 + c) * 16) = v;
    }
  }

  // elementwise mapping: thread -> (group row rl, 4 h-cols)
  const int rl  = tid >> 2;            // 0..63
  const int jq  = tid & 3;
  const int grow = g * 64 + rl;        // global batch row
  const int hc0  = b * 16 + jq * 4;

  f32x4 cc = *(const f32x4*)(c0 + (size_t)grow * HH + hc0);
  f32x4 bi0 = *(const f32x4*)(bias + 0 * HH + hc0);
  f32x4 bi1 = *(const f32x4*)(bias + 1 * HH + hc0);
  f32x4 bi2 = *(const f32x4*)(bias + 2 * HH + hc0);
  f32x4 bi3 = *(const f32x4*)(bias + 3 * HH + hc0);

  __syncthreads();   // Wh ready

#pragma unroll 1
  for (int t = 0; t < TT; ++t) {
    // ---- prefetch gx (4x8B) + resets before the poll ----
    uint2 gxr0 = *(const uint2*)(gx + ((size_t)(t * BB + grow)) * 4096 + 0 * 1024 + hc0);
    uint2 gxr1 = *(const uint2*)(gx + ((size_t)(t * BB + grow)) * 4096 + 1 * 1024 + hc0);
    uint2 gxr2 = *(const uint2*)(gx + ((size_t)(t * BB + grow)) * 4096 + 2 * 1024 + hc0);
    uint2 gxr3 = *(const uint2*)(gx + ((size_t)(t * BB + grow)) * 4096 + 3 * 1024 + hc0);
    bool rc, rn = false;
    if (byteMode) {
      rc = resetsB[t * BB + grow] != 0;
      if (t + 1 < TT) rn = resetsB[(t + 1) * BB + grow] != 0;
    } else {
      rc = resetsI[t * BB + grow] != 0;
      if (t + 1 < TT) rn = resetsI[(t + 1) * BB + grow] != 0;
    }

    // ---- poll own group's 64 producer flags ----
    {
      const unsigned int need = (unsigned int)(t + 1);
      const unsigned int* fp = flags + g * 64;
      while (true) {
        unsigned int v = __hip_atomic_load(&fp[ln], __ATOMIC_RELAXED,
                                           __HIP_MEMORY_SCOPE_AGENT);
        if (__all(v >= need)) break;
        __builtin_amdgcn_s_sleep(2);
      }
    }
    asm volatile("s_waitcnt vmcnt(0)" ::: "memory");
    __builtin_amdgcn_sched_barrier(0);

    // ---- h MFMA phase: 32 coalesced staged loads, counted vmcnt, pipelined B ----
    f32x16 ac0 = {0.f,0.f,0.f,0.f, 0.f,0.f,0.f,0.f, 0.f,0.f,0.f,0.f, 0.f,0.f,0.f,0.f};
    f32x16 ac1 = {0.f,0.f,0.f,0.f, 0.f,0.f,0.f,0.f, 0.f,0.f,0.f,0.f, 0.f,0.f,0.f,0.f};
    {
      const char* hbB = (const char*)hbufB + (size_t)(t & 1) * HSLOT
                      + (size_t)(g * 2 + wm) * 65536 + (size_t)wn * 32768
                      + (size_t)l31 * 16;
      bf8 ha[32];
      HI(0);  HI(1);  HI(2);  HI(3);  HI(4);  HI(5);  HI(6);  HI(7);
      HI(8);  HI(9);  HI(10); HI(11); HI(12); HI(13); HI(14); HI(15);
      HI(16); HI(17); HI(18); HI(19); HI(20); HI(21); HI(22); HI(23);
      HI(24); HI(25); HI(26); HI(27); HI(28); HI(29); HI(30); HI(31);
      bf8 cb0 = BRD(0, 0), cb1 = BRD(0, 1);
      HC(0, 31);  HC(1, 30);  HC(2, 29);  HC(3, 28);
      HC(4, 27);  HC(5, 26);  HC(6, 25);  HC(7, 24);
      HC(8, 23);  HC(9, 22);  HC(10, 21); HC(11, 20);
      HC(12, 19); HC(13, 18); HC(14, 17); HC(15, 16);
      HC(16, 15); HC(17, 14); HC(18, 13); HC(19, 12);
      HC(20, 11); HC(21, 10); HC(22, 9);  HC(23, 8);
      HC(24, 7);  HC(25, 6);  HC(26, 5);  HC(27, 4);
      HC(28, 3);  HC(29, 2);  HC(30, 1);  HC(31, 0);
    }

    // ---- combine K halves: wn1 -> TMP, wn0 adds, writes GL (aliased region) ----
    if (wn == 1) {
#pragma unroll
      for (int r = 0; r < 16; ++r) {
        const int rowl = (r & 3) + 8 * (r >> 2) + 4 * lhi;
        TG[((wm * 2 + 0) * 32 + rowl) * 32 + l31] = ac0[r];
        TG[((wm * 2 + 1) * 32 + rowl) * 32 + l31] = ac1[r];
      }
    }
    __syncthreads();
    float s0[16], s1[16];
    if (wn == 0) {
#pragma unroll
      for (int r = 0; r < 16; ++r) {
        const int rowl = (r & 3) + 8 * (r >> 2) + 4 * lhi;
        s0[r] = TG[((wm * 2 + 0) * 32 + rowl) * 32 + l31];
        s1[r] = TG[((wm * 2 + 1) * 32 + rowl) * 32 + l31];
      }
    }
    __syncthreads();
    if (wn == 0) {
#pragma unroll
      for (int r = 0; r < 16; ++r) {
        const int rowl = (r & 3) + 8 * (r >> 2) + 4 * lhi;
        TG[(wm * 32 + rowl) * 64 + l31]      = ac0[r] + s0[r];   // col tile 0
        TG[(wm * 32 + rowl) * 64 + 32 + l31] = ac1[r] + s1[r];   // col tile 1
      }
    }
    __syncthreads();   // GL ready

    // ---- elementwise LSTM: 4 cells (1 row x 4 h-cols) per thread ----
    const float* GLr = TG + rl * 64;
    f32x4 vi = *(const f32x4*)(GLr +      jq * 4);
    f32x4 vf = *(const f32x4*)(GLr + 16 + jq * 4);
    f32x4 vg = *(const f32x4*)(GLr + 32 + jq * 4);
    f32x4 vo = *(const f32x4*)(GLr + 48 + jq * 4);

    f32x4 nh, nc;
#pragma unroll
    for (int q = 0; q < 4; ++q) {
      const unsigned int pi = (q < 2) ? gxr0.x : gxr0.y;
      const unsigned int pf = (q < 2) ? gxr1.x : gxr1.y;
      const unsigned int pg = (q < 2) ? gxr2.x : gxr2.y;
      const unsigned int po = (q < 2) ? gxr3.x : gxr3.y;
      const int sh = (q & 1) * 16;
      const float ig = vi[q] + bf2f((unsigned short)(pi >> sh)) + bi0[q];
      const float fg = vf[q] + bf2f((unsigned short)(pf >> sh)) + bi1[q];
      const float gg = vg[q] + bf2f((unsigned short)(pg >> sh)) + bi2[q];
      const float og = vo[q] + bf2f((unsigned short)(po >> sh)) + bi3[q];
      const float cold = rc ? 0.f : cc[q];
      const float c2 = sigm(fg) * cold + sigm(ig) * ftanh(gg);
      nc[q] = c2;
      nh[q] = sigm(og) * ftanh(c2);
    }
    cc = nc;

    // ---- publish h (8B coherent store) + flag, then bulk out stores ----
    if (t + 1 < TT) {
      uint2 hp;
      float h0v = rn ? 0.f : nh[0], h1v = rn ? 0.f : nh[1];
      float h2v = rn ? 0.f : nh[2], h3v = rn ? 0.f : nh[3];
      asm("v_cvt_pk_bf16_f32 %0, %1, %2" : "=v"(hp.x) : "v"(h0v), "v"(h1v));
      asm("v_cvt_pk_bf16_f32 %0, %1, %2" : "=v"(hp.y) : "v"(h2v), "v"(h3v));
      char* dst = (char*)hbufB + (size_t)((t + 1) & 1) * HSLOT
                + (((size_t)(grow >> 5) * 128 + (hc0 >> 3)) * 256
                   + (size_t)(grow & 31) * 8 + (hc0 & 7)) * 2;
      asm volatile("global_store_dwordx2 %0, %1, off sc0 sc1" :: "v"(dst), "v"(hp) : "memory");
      asm volatile("s_waitcnt vmcnt(0)" ::: "memory");
      __syncthreads();
      if (tid == 0) {
        unsigned int* fp = flags + bid;
        const unsigned int val = (unsigned int)(t + 2);
        asm volatile("global_store_dword %0, %1, off sc0 sc1" :: "v"(fp), "v"(val) : "memory");
      }
      *(f32x4*)(out + (size_t)t * BB * HH + (size_t)grow * HH + hc0) = nh;
    } else {
      *(f32x4*)(out + (size_t)t * BB * HH + (size_t)grow * HH + hc0) = nh;
      *(f32x4*)(out + (size_t)TT * BB * HH + (size_t)grow * HH + hc0) = nh;
      *(f32x4*)(out + (size_t)TT * BB * HH + (size_t)BB * HH + (size_t)grow * HH + hc0) = nc;
    }
  }
}

// ---------------- fallback (round-3 kernel, ws too small) ----------------
#define FB_GL_OFF 131072
#define FB_HN_OFF 147968
#define FB_SMEM   150016

#define FB_HLD(dst, KH) asm volatile("global_load_dwordx4 %0, %1, off sc0 sc1" \
    : "=v"(dst) : "v"(hbB + (size_t)(KH) * 64) : "memory")
#define FB_HSTEP(IT, WCA, WCB) do {                                                  \
  asm volatile("s_waitcnt vmcnt(" WCA ")" ::: "memory");                             \
  __builtin_amdgcn_sched_barrier(0);                                                 \
  { const bf8 bbA = *(const bf8*)(sm + (size_t)(128 + 8*(IT) + 2*wk + lhi)*512 + l31*16); \
    acc = __builtin_amdgcn_mfma_f32_32x32x16_bf16(hA, bbA, acc, 0, 0, 0); }          \
  if ((IT) < 15) FB_HLD(hA, 2*(IT) + 2);                                             \
  asm volatile("s_waitcnt vmcnt(" WCB ")" ::: "memory");                             \
  __builtin_amdgcn_sched_barrier(0);                                                 \
  { const bf8 bbB = *(const bf8*)(sm + (size_t)(128 + 8*(IT) + 4 + 2*wk + lhi)*512 + l31*16); \
    acc = __builtin_amdgcn_mfma_f32_32x32x16_bf16(hB, bbB, acc, 0, 0, 0); }          \
  if ((IT) < 15) FB_HLD(hB, 2*(IT) + 3);                                             \
} while (0)

__global__ void __launch_bounds__(512)
k_scan_fb(const float* __restrict__ obs, const unsigned char* __restrict__ resetsB,
          const int* __restrict__ resetsI, const float* __restrict__ c0,
          const float* __restrict__ bias, const unsigned short* __restrict__ Wp,
          unsigned short* __restrict__ hbuf, unsigned int* __restrict__ flags,
          const int* __restrict__ flagmode, float* __restrict__ out) {
  extern __shared__ char sm[];
  float* GLf = (float*)(sm + FB_GL_OFF);
  unsigned short* HNp = (unsigned short*)(sm + FB_HN_OFF);

  const int tid = threadIdx.x;
  const int w   = tid >> 6;
  const int wm  = w >> 1;
  const int wk  = w & 1;
  const int ln  = tid & 63;
  const int l31 = ln & 31;
  const int lhi = ln >> 5;
  const int b   = blockIdx.x;
  const int byteMode = *flagmode;

  {
    const int np_ld = tid >> 4;
    const int seg   = tid & 15;
    const int gq = np_ld >> 3, jj = np_ld & 7;
    const unsigned short* src = Wp + (size_t)(gq * 1024 + b * 8 + jj) * KT;
#pragma unroll 4
    for (int i = 0; i < 16; ++i) {
      const int k8 = seg * 16 + i;
      bf8 v = *(const bf8*)(src + k8 * 8);
      *(bf8*)(sm + (size_t)k8 * 512 + np_ld * 16) = v;
    }
  }

  const int j  = tid & 7;
  const int rl = tid >> 3;
  float c_a = c0[(size_t)rl * HH + b * 8 + j];
  float c_b = c0[(size_t)(rl + 64) * HH + b * 8 + j];
  const float wbias = bias[(l31 >> 3) * 1024 + b * 8 + (l31 & 7)];

  __syncthreads();

#pragma unroll 1
  for (int t = 0; t < TT; ++t) {
    bool rc0, rc1, rn0 = false, rn1 = false;
    if (byteMode) {
      rc0 = resetsB[t * BB + rl] != 0;  rc1 = resetsB[t * BB + rl + 64] != 0;
      if (t + 1 < TT) { rn0 = resetsB[(t+1)*BB + rl] != 0; rn1 = resetsB[(t+1)*BB + rl + 64] != 0; }
    } else {
      rc0 = resetsI[t * BB + rl] != 0;  rc1 = resetsI[t * BB + rl + 64] != 0;
      if (t + 1 < TT) { rn0 = resetsI[(t+1)*BB + rl] != 0; rn1 = resetsI[(t+1)*BB + rl + 64] != 0; }
    }

    f32x16 acc = {0.f,0.f,0.f,0.f, 0.f,0.f,0.f,0.f, 0.f,0.f,0.f,0.f, 0.f,0.f,0.f,0.f};

    {
      const float* xbase = obs + ((size_t)t * BB + wm * 32 + l31) * DD + wk * 16 + lhi * 8;
#pragma unroll 8
      for (int ks = 0; ks < 32; ++ks) {
        const float* xp = xbase + ks * 32;
        f32x4 f0 = *(const f32x4*)xp;
        f32x4 f1 = *(const f32x4*)(xp + 4);
        uint4 cv;
        asm("v_cvt_pk_bf16_f32 %0, %1, %2" : "=v"(cv.x) : "v"(f0[0]), "v"(f0[1]));
        asm("v_cvt_pk_bf16_f32 %0, %1, %2" : "=v"(cv.y) : "v"(f0[2]), "v"(f0[3]));
        asm("v_cvt_pk_bf16_f32 %0, %1, %2" : "=v"(cv.z) : "v"(f1[0]), "v"(f1[1]));
        asm("v_cvt_pk_bf16_f32 %0, %1, %2" : "=v"(cv.w) : "v"(f1[2]), "v"(f1[3]));
        const bf8 xa = __builtin_bit_cast(bf8, cv);
        const bf8 xb = *(const bf8*)(sm + (size_t)(4 * ks + 2 * wk + lhi) * 512 + l31 * 16);
        acc = __builtin_amdgcn_mfma_f32_32x32x16_bf16(xa, xb, acc, 0, 0, 0);
      }
    }

    {
      const unsigned long long* f64 = (const unsigned long long*)flags;
      const unsigned int need = (unsigned int)(t + 1);
      while (true) {
        unsigned long long v = __hip_atomic_load(&f64[ln], __ATOMIC_RELAXED,
                                                 __HIP_MEMORY_SCOPE_AGENT);
        const int ok = ((unsigned int)v >= need) && ((unsigned int)(v >> 32) >= need);
        if (__all(ok)) break;
        __builtin_amdgcn_s_sleep(2);
      }
    }
    asm volatile("s_waitcnt vmcnt(0)" ::: "memory");
    __builtin_amdgcn_sched_barrier(0);

    {
      const char* hbB = (const char*)hbuf + (size_t)(t & 1) * (BB * HH * 2)
                      + (size_t)(wm * 32 + l31) * (HH * 2) + (size_t)wk * 32 + (size_t)lhi * 16;
      bf8 hA, hB;
      FB_HLD(hA, 0); FB_HLD(hB, 1);
      FB_HSTEP(0,  "1", "1");  FB_HSTEP(1,  "1", "1");  FB_HSTEP(2,  "1", "1");
      FB_HSTEP(3,  "1", "1");  FB_HSTEP(4,  "1", "1");  FB_HSTEP(5,  "1", "1");
      FB_HSTEP(6,  "1", "1");  FB_HSTEP(7,  "1", "1");  FB_HSTEP(8,  "1", "1");
      FB_HSTEP(9,  "1", "1");  FB_HSTEP(10, "1", "1");  FB_HSTEP(11, "1", "1");
      FB_HSTEP(12, "1", "1");  FB_HSTEP(13, "1", "1");  FB_HSTEP(14, "1", "1");
      FB_HSTEP(15, "1", "0");
    }

    if (wk == 1) {
      char* tp = sm + FB_GL_OFF + wm * 4096 + ln * 16;
      f32x4 v0 = {acc[0], acc[1], acc[2], acc[3]};
      f32x4 v1 = {acc[4], acc[5], acc[6], acc[7]};
      f32x4 v2 = {acc[8], acc[9], acc[10], acc[11]};
      f32x4 v3 = {acc[12], acc[13], acc[14], acc[15]};
      *(f32x4*)(tp)        = v0;  *(f32x4*)(tp + 1024) = v1;
      *(f32x4*)(tp + 2048) = v2;  *(f32x4*)(tp + 3072) = v3;
    }
    __syncthreads();
    f32x4 r0, r1, r2, r3;
    if (wk == 0) {
      const char* tp = sm + FB_GL_OFF + wm * 4096 + ln * 16;
      r0 = *(const f32x4*)(tp);        r1 = *(const f32x4*)(tp + 1024);
      r2 = *(const f32x4*)(tp + 2048); r3 = *(const f32x4*)(tp + 3072);
    }
    __syncthreads();
    if (wk == 0) {
#pragma unroll
      for (int r = 0; r < 16; ++r) {
        const float add = (r < 4) ? r0[r & 3] : (r < 8) ? r1[r & 3]
                        : (r < 12) ? r2[r & 3] : r3[r & 3];
        const int rowl = wm * 32 + (r & 3) + 8 * (r >> 2) + 4 * lhi;
        GLf[rowl * 33 + l31] = acc[r] + add + wbias;
      }
    }
    __syncthreads();

    {
      {
        const int row = rl;
        float cold = rc0 ? 0.f : c_a;
        const float ig = GLf[row * 33 + j],      fg = GLf[row * 33 + 8 + j];
        const float gg = GLf[row * 33 + 16 + j], og = GLf[row * 33 + 24 + j];
        const float nc = sigm(fg) * cold + sigm(ig) * ftanh(gg);
        const float nh = sigm(og) * ftanh(nc);
        c_a = nc;
        out[(size_t)t * BB * HH + (size_t)row * HH + b * 8 + j] = nh;
        HNp[row * 8 + j] = rn0 ? (unsigned short)0 : f2bf(nh);
        if (t == TT - 1) {
          out[(size_t)TT * BB * HH + (size_t)row * HH + b * 8 + j] = nh;
          out[(size_t)TT * BB * HH + (size_t)BB * HH + (size_t)row * HH + b * 8 + j] = nc;
        }
      }
      {
        const int row = rl + 64;
        float cold = rc1 ? 0.f : c_b;
        const float ig = GLf[row * 33 + j],      fg = GLf[row * 33 + 8 + j];
        const float gg = GLf[row * 33 + 16 + j], og = GLf[row * 33 + 24 + j];
        const float nc = sigm(fg) * cold + sigm(ig) * ftanh(gg);
        const float nh = sigm(og) * ftanh(nc);
        c_b = nc;
        out[(size_t)t * BB * HH + (size_t)row * HH + b * 8 + j] = nh;
        HNp[row * 8 + j] = rn1 ? (unsigned short)0 : f2bf(nh);
        if (t == TT - 1) {
          out[(size_t)TT * BB * HH + (size_t)row * HH + b * 8 + j] = nh;
          out[(size_t)TT * BB * HH + (size_t)BB * HH + (size_t)row * HH + b * 8 + j] = nc;
        }
      }
    }
    __syncthreads();

    if (t + 1 < TT) {
      if (tid < BB) {
        const bf8 hv = *(const bf8*)(sm + FB_HN_OFF + tid * 16);
        char* dst = (char*)hbuf + (size_t)((t + 1) & 1) * (BB * HH * 2)
                  + (size_t)tid * (HH * 2) + (size_t)b * 16;
        asm volatile("global_store_dwordx4 %0, %1, off sc0 sc1" :: "v"(dst), "v"(hv) : "memory");
      }
      asm volatile("s_waitcnt vmcnt(0)" ::: "memory");
      __syncthreads();
      if (tid == 0) {
        unsigned int* fp = flags + b;
        const unsigned int val = (unsigned int)(t + 2);
        asm volatile("global_store_dword %0, %1, off sc0 sc1" :: "v"(fp), "v"(val) : "memory");
      }
    }
  }
}

// ---------------- launch ----------------

extern "C" void kernel_launch(void* const* d_in, const int* in_sizes, int n_in,
                              void* d_out, int out_size, void* d_ws, size_t ws_size,
                              hipStream_t stream) {
  const float* obs  = (const float*)d_in[0];
  const void*  rst  = d_in[1];
  const float* h0   = (const float*)d_in[2];
  const float* c0   = (const float*)d_in[3];
  const float* Wx   = (const float*)d_in[4];
  const float* Wh   = (const float*)d_in[5];
  const float* bias = (const float*)d_in[6];
  float* out = (float*)d_out;

  char* ws = (char*)d_ws;
  const size_t WP_OFF    = 0;                                   // 16 MiB
  const size_t HBUF_OFF  = (size_t)16 << 20;                    // 0.5 MiB (fallback)
  const size_t FLAGS_OFF = HBUF_OFF + ((size_t)512 << 10);
  const size_t HBUFB_OFF = (size_t)17 << 20;                    // 0.5 MiB (staged layout)
  const size_t OBSBF_OFF = (size_t)24 << 20;                    // 128 MiB
  const size_t GX_OFF    = OBSBF_OFF + ((size_t)128 << 20);     // 512 MiB
  const size_t WS_NEED   = GX_OFF + (size_t)TT * BB * NG * 2;

  unsigned short* Wp    = (unsigned short*)(ws + WP_OFF);
  unsigned short* hbuf  = (unsigned short*)(ws + HBUF_OFF);
  unsigned int*   flags = (unsigned int*)(ws + FLAGS_OFF);
  int*        flagmode  = (int*)(flags + 256);
  unsigned short* hbufB = (unsigned short*)(ws + HBUFB_OFF);
  unsigned short* obsbf = (unsigned short*)(ws + OBSBF_OFF);
  unsigned short* gxp   = (unsigned short*)(ws + GX_OFF);

  const unsigned char* rB = (const unsigned char*)rst;
  const int* rI = (const int*)rst;

  k_detect<<<1, 256, 0, stream>>>((const unsigned int*)rst, flagmode, flags);
  k_pack<<<dim3((KT / 64) * (NG / 64)), dim3(256), 0, stream>>>(Wx, Wh, Wp);

  if (ws_size >= WS_NEED) {
    k_initB<<<dim3((BB * HH) / 256), dim3(256), 0, stream>>>(h0, rB, rI, flagmode, hbufB);
    k_cvt<<<dim3(2048), dim3(256), 0, stream>>>(obs, obsbf);
    hipFuncSetAttribute((const void*)k_gemm,
                        hipFuncAttributeMaxDynamicSharedMemorySize, GEMM_SMEM);
    k_gemm<<<dim3((TT * BB / 128) * (NG / 128)), dim3(256), GEMM_SMEM, stream>>>(
        obsbf, Wp, gxp);
    hipFuncSetAttribute((const void*)k_scanh2,
                        hipFuncAttributeMaxDynamicSharedMemorySize, SCANH2_SMEM);
    k_scanh2<<<dim3(NBLK), dim3(256), SCANH2_SMEM, stream>>>(
        rB, rI, c0, bias, Wp, gxp, hbufB, flags, flagmode, out);
  } else {
    k_init<<<dim3((BB * HH) / 256), dim3(256), 0, stream>>>(h0, rB, rI, flagmode, hbuf);
    hipFuncSetAttribute((const void*)k_scan_fb,
                        hipFuncAttributeMaxDynamicSharedMemorySize, FB_SMEM);
    k_scan_fb<<<dim3(NBLK), dim3(512), FB_SMEM, stream>>>(
        obs, rB, rI, c0, bias, Wp, hbuf, flags, flagmode, out);
  }
}

// Round 8
// 2625.323 us; speedup vs baseline: 9.7139x; 1.2693x over previous
//
#include <hip/hip_runtime.h>
#include <hip/hip_bf16.h>

// Problem dims
#define TT 512
#define BB 128
#define DD 1024
#define HH 1024
#define NG 4096    // 4*HH gate columns
#define KT 2048    // DD+HH

using bf8    = __attribute__((ext_vector_type(8))) short;   // 8 bf16 bit patterns
using f32x4  = __attribute__((ext_vector_type(4))) float;
using f32x16 = __attribute__((ext_vector_type(16))) float;

__device__ __forceinline__ unsigned short f2bf(float f) {
  unsigned int u = __builtin_bit_cast(unsigned int, f);
  u += 0x7fffu + ((u >> 16) & 1u);   // RNE
  return (unsigned short)(u >> 16);
}
__device__ __forceinline__ float bf2f(unsigned short u) {
  unsigned int x = ((unsigned int)u) << 16;
  return __builtin_bit_cast(float, x);
}
__device__ __forceinline__ float sigm(float x) { return 1.0f / (1.0f + __expf(-x)); }
__device__ __forceinline__ float ftanh(float x) {
  float e = __expf(2.0f * x);
  return 1.0f - 2.0f / (e + 1.0f);
}

// ---------------- prep kernels ----------------

__global__ void k_detect(const unsigned int* __restrict__ rw, int* __restrict__ flagmode,
                         unsigned int* __restrict__ flags) {
  __shared__ int any;
  if (threadIdx.x == 0) any = 0;
  __syncthreads();
  int loc = 0;
  for (int i = threadIdx.x; i < (TT * BB) / 4; i += blockDim.x)
    if (rw[i] > 1u) loc = 1;
  if (loc) atomicOr(&any, 1);
  __syncthreads();
  if (threadIdx.x == 0) *flagmode = any;
  flags[threadIdx.x] = 1u;   // all 256 producer flags: h-input for step 0 ready
}

// Pack W = [Wx; Wh] (KT x NG, f32 row-major) into Wp[n][k] bf16 (N-major).
__global__ void k_pack(const float* __restrict__ Wx, const float* __restrict__ Wh,
                       unsigned short* __restrict__ Wp) {
  __shared__ unsigned short tile[64][65];
  const int kt = blockIdx.x & 31;
  const int nt = blockIdx.x >> 5;
  const int k0 = kt * 64, n0 = nt * 64;
  const int t = threadIdx.x;
  {
    const int kl = t >> 2;
    const int nl = (t & 3) * 16;
    const int kg = k0 + kl;
    const float* src = (kg < DD) ? (Wx + (size_t)kg * NG + n0 + nl)
                                 : (Wh + (size_t)(kg - DD) * NG + n0 + nl);
#pragma unroll
    for (int j = 0; j < 16; ++j) tile[kl][nl + j] = f2bf(src[j]);
  }
  __syncthreads();
  {
    const int nl = t >> 2;
    const int kl = (t & 3) * 16;
    unsigned short* dst = Wp + (size_t)(n0 + nl) * KT + k0 + kl;
#pragma unroll
    for (int j = 0; j < 16; ++j) dst[j] = tile[kl + j][nl];
  }
}

// old-layout hbuf init (fallback path)
__global__ void k_init(const float* __restrict__ h0, const unsigned char* __restrict__ rB,
                       const int* __restrict__ rI, const int* __restrict__ flagmode,
                       unsigned short* __restrict__ hbuf) {
  const int i = blockIdx.x * 256 + threadIdx.x;
  if (i >= BB * HH) return;
  const int row = i >> 10;
  const bool r = (*flagmode) ? (rB[row] != 0) : (rI[row] != 0);
  hbuf[i] = r ? (unsigned short)0 : f2bf(h0[i]);
}

// staged-layout hbufB init: per group [ci 0..63][lhi 0..1][row32][8]
__global__ void k_initB3(const float* __restrict__ h0, const unsigned char* __restrict__ rB,
                         const int* __restrict__ rI, const int* __restrict__ flagmode,
                         unsigned short* __restrict__ hbufB) {
  const int i = blockIdx.x * 256 + threadIdx.x;
  if (i >= BB * HH) return;
  const int row = i >> 10, hcol = i & 1023;
  const bool r = (*flagmode) ? (rB[row] != 0) : (rI[row] != 0);
  const unsigned short val = r ? (unsigned short)0 : f2bf(h0[i]);
  const int g = row >> 5, rl = row & 31;
  const size_t e = (size_t)g * 32768 + (size_t)(hcol >> 4) * 512
                 + (size_t)((hcol >> 3) & 1) * 256 + (size_t)rl * 8 + (hcol & 7);
  hbufB[e] = val;
}

// obs f32 -> bf16
__global__ void k_cvt(const float* __restrict__ src, unsigned short* __restrict__ dst) {
  size_t i = ((size_t)blockIdx.x * 256 + threadIdx.x) * 8;
  const size_t stride = (size_t)2048 * 256 * 8;
  for (; i < (size_t)TT * BB * DD; i += stride) {
    f32x4 a = *(const f32x4*)(src + i);
    f32x4 c = *(const f32x4*)(src + i + 4);
    uint4 cv;
    asm("v_cvt_pk_bf16_f32 %0, %1, %2" : "=v"(cv.x) : "v"(a[0]), "v"(a[1]));
    asm("v_cvt_pk_bf16_f32 %0, %1, %2" : "=v"(cv.y) : "v"(a[2]), "v"(a[3]));
    asm("v_cvt_pk_bf16_f32 %0, %1, %2" : "=v"(cv.z) : "v"(c[0]), "v"(c[1]));
    asm("v_cvt_pk_bf16_f32 %0, %1, %2" : "=v"(cv.w) : "v"(c[2]), "v"(c[3]));
    *(bf8*)(dst + i) = __builtin_bit_cast(bf8, cv);
  }
}

// ---------------- gx = obs_bf @ Wx  (unchanged from round 4) ----------------
#define GEMM_SMEM 69632

__global__ void __launch_bounds__(256)
k_gemm(const unsigned short* __restrict__ A, const unsigned short* __restrict__ Bw,
       unsigned short* __restrict__ C) {
  extern __shared__ char gsm[];
  const int tid = threadIdx.x;
  const int w = tid >> 6, l = tid & 63;
  const int l15 = l & 15, lh4 = l >> 4;
  const int wm2 = w >> 1, wn2 = w & 1;
  const int mt = blockIdx.x >> 5, nt = blockIdx.x & 31;
  const size_t m0 = (size_t)mt * 128, n0 = (size_t)nt * 128;

  f32x4 acc[4][4] = {};

  const int srow = l >> 3;
  const int schunk = (l & 7) ^ srow;

  const unsigned short* Ag[4];
  const unsigned short* Bg[4];
#pragma unroll
  for (int i = 0; i < 4; ++i) {
    const int r = w * 32 + i * 8 + srow;
    Ag[i] = A + (m0 + r) * 1024 + schunk * 8;
    Bg[i] = Bw + (n0 + r) * 2048 + schunk * 8;
  }

#define GSTAGE(BUF, KS) do {                                                        \
    const size_t ko_ = (size_t)(KS) * 64;                                           \
    char* base_ = gsm + (BUF) * 32768;                                              \
    _Pragma("unroll")                                                               \
    for (int i_ = 0; i_ < 4; ++i_) {                                                \
      __builtin_amdgcn_global_load_lds(                                             \
        (const __attribute__((address_space(1))) unsigned int*)(Ag[i_] + ko_),      \
        (__attribute__((address_space(3))) unsigned int*)(base_ + (w*32 + i_*8)*128), \
        16, 0, 0);                                                                  \
      __builtin_amdgcn_global_load_lds(                                             \
        (const __attribute__((address_space(1))) unsigned int*)(Bg[i_] + ko_),      \
        (__attribute__((address_space(3))) unsigned int*)(base_ + 16384 + (w*32 + i_*8)*128), \
        16, 0, 0);                                                                  \
    }                                                                               \
  } while (0)

#define GCOMP(BUF) do {                                                             \
    const char* bA_ = gsm + (BUF) * 32768;                                          \
    const char* bB_ = bA_ + 16384;                                                  \
    _Pragma("unroll")                                                               \
    for (int kk_ = 0; kk_ < 2; ++kk_) {                                             \
      bf8 af_[4], bf_[4];                                                           \
      _Pragma("unroll")                                                             \
      for (int mi_ = 0; mi_ < 4; ++mi_) {                                           \
        const int r_ = wm2 * 64 + mi_ * 16 + l15;                                   \
        af_[mi_] = *(const bf8*)(bA_ + r_ * 128 + ((kk_*64 + lh4*16) ^ ((r_ & 7) << 4))); \
      }                                                                             \
      _Pragma("unroll")                                                             \
      for (int ni_ = 0; ni_ < 4; ++ni_) {                                           \
        const int r_ = wn2 * 64 + ni_ * 16 + l15;                                   \
        bf_[ni_] = *(const bf8*)(bB_ + r_ * 128 + ((kk_*64 + lh4*16) ^ ((r_ & 7) << 4))); \
      }                                                                             \
      _Pragma("unroll")                                                             \
      for (int mi_ = 0; mi_ < 4; ++mi_)                                             \
        _Pragma("unroll")                                                           \
        for (int ni_ = 0; ni_ < 4; ++ni_)                                           \
          acc[mi_][ni_] = __builtin_amdgcn_mfma_f32_16x16x32_bf16(                  \
              af_[mi_], bf_[ni_], acc[mi_][ni_], 0, 0, 0);                          \
    }                                                                               \
  } while (0)

  GSTAGE(0, 0);
  asm volatile("s_waitcnt vmcnt(0)" ::: "memory");
  __syncthreads();
#pragma unroll 1
  for (int ks = 0; ks < 16; ++ks) {
    if (ks < 15) GSTAGE((ks + 1) & 1, ks + 1);
    GCOMP(ks & 1);
    if (ks < 15) {
      asm volatile("s_waitcnt vmcnt(0)" ::: "memory");
      __syncthreads();
    }
  }

  __syncthreads();
  float* ct = (float*)(gsm + w * 17408);   // [64][68] f32
#pragma unroll
  for (int mi = 0; mi < 4; ++mi)
#pragma unroll
    for (int ni = 0; ni < 4; ++ni)
#pragma unroll
      for (int q = 0; q < 4; ++q)
        ct[(mi * 16 + lh4 * 4 + q) * 68 + ni * 16 + l15] = acc[mi][ni][q];
#pragma unroll
  for (int i = 0; i < 8; ++i) {
    const int row = i * 8 + (l >> 3);
    const int c8 = (l & 7) * 8;
    f32x4 v0 = *(const f32x4*)(ct + row * 68 + c8);
    f32x4 v1 = *(const f32x4*)(ct + row * 68 + c8 + 4);
    uint4 cv;
    asm("v_cvt_pk_bf16_f32 %0, %1, %2" : "=v"(cv.x) : "v"(v0[0]), "v"(v0[1]));
    asm("v_cvt_pk_bf16_f32 %0, %1, %2" : "=v"(cv.y) : "v"(v0[2]), "v"(v0[3]));
    asm("v_cvt_pk_bf16_f32 %0, %1, %2" : "=v"(cv.z) : "v"(v1[0]), "v"(v1[1]));
    asm("v_cvt_pk_bf16_f32 %0, %1, %2" : "=v"(cv.w) : "v"(v1[2]), "v"(v1[3]));
    *(bf8*)(C + (m0 + wm2 * 64 + row) * 4096 + n0 + wn2 * 64 + c8) =
        __builtin_bit_cast(bf8, cv);
  }
#undef GSTAGE
#undef GCOMP
}

// ---------------- serial h-scan v3: 4 groups x 64 blocks (256 blocks, all CUs) ----------------
// LDS: Wl [k8 0..127][c 0..63][16B] @0 (131072); TMP 3x8KB @131072; GL [32][66] f32 aliases TMP
#define SCANH3_SMEM 155648
#define HSLOT3 262144   // 4 groups * 64KB per slot
#define TMP3_OFF 131072

#define HI3(I) asm volatile("global_load_dwordx4 %0, %1, off sc0 sc1" \
    : "=v"(ha[I]) : "v"(hbB + (I) * 1024) : "memory")

// B fragment: global k16-chunk CI, col-tile CN: Wl[(CI*2+lhi)][CN*32+l31]
#define BRD3(CI, CN) (*(const bf8*)(sm + \
    (size_t)((((CI) * 2 + lhi) * 64 + (CN) * 32 + l31)) * 16))

#define HC3(CI, VM) do {                                                  \
    bf8 nb0, nb1;                                                         \
    if ((CI) < 15) { nb0 = BRD3(kc0 + (CI) + 1, 0); nb1 = BRD3(kc0 + (CI) + 1, 1); } \
    asm volatile("s_waitcnt vmcnt(" #VM ")" ::: "memory");                \
    __builtin_amdgcn_sched_barrier(0);                                    \
    ac0 = __builtin_amdgcn_mfma_f32_32x32x16_bf16(ha[CI], cb0, ac0, 0, 0, 0); \
    ac1 = __builtin_amdgcn_mfma_f32_32x32x16_bf16(ha[CI], cb1, ac1, 0, 0, 0); \
    cb0 = nb0; cb1 = nb1;                                                 \
  } while (0)

__global__ void __launch_bounds__(256)
k_scanh3(const unsigned char* __restrict__ resetsB, const int* __restrict__ resetsI,
         const float* __restrict__ c0, const float* __restrict__ bias,
         const unsigned short* __restrict__ Wp, const unsigned short* __restrict__ gx,
         unsigned short* __restrict__ hbufB, unsigned int* __restrict__ flags,
         const int* __restrict__ flagmode, float* __restrict__ out) {
  extern __shared__ char sm[];
  float* TG = (float*)(sm + TMP3_OFF);   // TMP regions then GL (aliased)

  const int tid = threadIdx.x;
  const int wq  = tid >> 6;        // K-quarter 0..3
  const int ln  = tid & 63;
  const int l31 = ln & 31;
  const int lhi = ln >> 5;
  const int kc0 = wq * 16;         // first global k16-chunk for this wave
  const int bid = blockIdx.x;
  const int g   = bid >> 6;        // batch group 0..3 (rows 32g..32g+31)
  const int b   = bid & 63;        // 16 h-cols per block
  const int byteMode = *flagmode;

  // ---- Wl slice -> LDS (once): [k8][c][8], c = gate*16 + hcl ----
  {
    const int c = tid >> 2, seg = tid & 3;
    const int n = (c >> 4) * 1024 + b * 16 + (c & 15);
    const unsigned short* src = Wp + (size_t)n * KT + 1024;
#pragma unroll 8
    for (int i = 0; i < 32; ++i) {
      const int k8 = seg * 32 + i;
      bf8 v = *(const bf8*)(src + k8 * 8);
      *(bf8*)(sm + ((size_t)k8 * 64 + c) * 16) = v;
    }
  }

  // elementwise mapping: thread -> (group row, 2 h-cols)
  const int row  = tid >> 3;           // 0..31
  const int jd   = tid & 7;
  const int grow = g * 32 + row;       // global batch row
  const int hc   = b * 16 + jd * 2;    // global h-col (even)

  float ccx = c0[(size_t)grow * HH + hc];
  float ccy = c0[(size_t)grow * HH + hc + 1];
  const float bx0 = bias[0 * HH + hc], by0 = bias[0 * HH + hc + 1];
  const float bx1 = bias[1 * HH + hc], by1 = bias[1 * HH + hc + 1];
  const float bx2 = bias[2 * HH + hc], by2 = bias[2 * HH + hc + 1];
  const float bx3 = bias[3 * HH + hc], by3 = bias[3 * HH + hc + 1];

  // publish byte-offset within group slot: [ci][lhi][row][kk]
  const size_t puboff = (size_t)(hc >> 4) * 1024 + (size_t)((hc >> 3) & 1) * 512
                      + (size_t)row * 16 + (size_t)(hc & 7) * 2;

  __syncthreads();   // Wl ready

#pragma unroll 1
  for (int t = 0; t < TT; ++t) {
    // ---- prefetch gx (4x4B) + resets before the poll ----
    const unsigned short* gp = gx + ((size_t)t * BB + grow) * 4096 + hc;
    const unsigned int gx0 = *(const unsigned int*)(gp);
    const unsigned int gx1 = *(const unsigned int*)(gp + 1024);
    const unsigned int gx2 = *(const unsigned int*)(gp + 2048);
    const unsigned int gx3 = *(const unsigned int*)(gp + 3072);
    bool rc, rn = false;
    if (byteMode) {
      rc = resetsB[t * BB + grow] != 0;
      if (t + 1 < TT) rn = resetsB[(t + 1) * BB + grow] != 0;
    } else {
      rc = resetsI[t * BB + grow] != 0;
      if (t + 1 < TT) rn = resetsI[(t + 1) * BB + grow] != 0;
    }

    // ---- poll own group's 64 producer flags ----
    {
      const unsigned int need = (unsigned int)(t + 1);
      const unsigned int* fp = flags + g * 64;
      while (true) {
        unsigned int v = __hip_atomic_load(&fp[ln], __ATOMIC_RELAXED,
                                           __HIP_MEMORY_SCOPE_AGENT);
        if (__all(v >= need)) break;
        __builtin_amdgcn_s_sleep(2);
      }
    }
    asm volatile("s_waitcnt vmcnt(0)" ::: "memory");
    __builtin_amdgcn_sched_barrier(0);

    // ---- h MFMA phase: 16 staged A-loads (this wave's K-quarter), counted vmcnt ----
    f32x16 ac0 = {0.f,0.f,0.f,0.f, 0.f,0.f,0.f,0.f, 0.f,0.f,0.f,0.f, 0.f,0.f,0.f,0.f};
    f32x16 ac1 = {0.f,0.f,0.f,0.f, 0.f,0.f,0.f,0.f, 0.f,0.f,0.f,0.f, 0.f,0.f,0.f,0.f};
    {
      const char* hbB = (const char*)hbufB + (size_t)(t & 1) * HSLOT3
                      + (size_t)g * 65536 + (size_t)kc0 * 1024
                      + (size_t)lhi * 512 + (size_t)l31 * 16;
      bf8 ha[16];
      HI3(0);  HI3(1);  HI3(2);  HI3(3);  HI3(4);  HI3(5);  HI3(6);  HI3(7);
      HI3(8);  HI3(9);  HI3(10); HI3(11); HI3(12); HI3(13); HI3(14); HI3(15);
      bf8 cb0 = BRD3(kc0, 0), cb1 = BRD3(kc0, 1);
      HC3(0, 15);  HC3(1, 14);  HC3(2, 13);  HC3(3, 12);
      HC3(4, 11);  HC3(5, 10);  HC3(6, 9);   HC3(7, 8);
      HC3(8, 7);   HC3(9, 6);   HC3(10, 5);  HC3(11, 4);
      HC3(12, 3);  HC3(13, 2);  HC3(14, 1);  HC3(15, 0);
    }

    // ---- 4-way K combine: waves 1..3 dump to TMP, wave 0 accumulates ----
    if (wq > 0) {
      char* tp = sm + TMP3_OFF + (wq - 1) * 8192 + ln * 16;
#pragma unroll
      for (int qd = 0; qd < 4; ++qd) {
        f32x4 v0 = {ac0[qd*4+0], ac0[qd*4+1], ac0[qd*4+2], ac0[qd*4+3]};
        f32x4 v1 = {ac1[qd*4+0], ac1[qd*4+1], ac1[qd*4+2], ac1[qd*4+3]};
        *(f32x4*)(tp + qd * 1024)        = v0;
        *(f32x4*)(tp + 4096 + qd * 1024) = v1;
      }
    }
    __syncthreads();
    if (wq == 0) {
#pragma unroll
      for (int s = 0; s < 3; ++s) {
        const char* tp = sm + TMP3_OFF + s * 8192 + ln * 16;
#pragma unroll
        for (int qd = 0; qd < 4; ++qd) {
          f32x4 v0 = *(const f32x4*)(tp + qd * 1024);
          f32x4 v1 = *(const f32x4*)(tp + 4096 + qd * 1024);
          ac0[qd*4+0] += v0[0]; ac0[qd*4+1] += v0[1];
          ac0[qd*4+2] += v0[2]; ac0[qd*4+3] += v0[3];
          ac1[qd*4+0] += v1[0]; ac1[qd*4+1] += v1[1];
          ac1[qd*4+2] += v1[2]; ac1[qd*4+3] += v1[3];
        }
      }
    }
    __syncthreads();   // TMP consumed; GL region reusable
    if (wq == 0) {
      // D layout 32x32: col = lane&31, row = (reg&3) + 8*(reg>>2) + 4*(lane>>5)
#pragma unroll
      for (int r = 0; r < 16; ++r) {
        const int rowl = (r & 3) + 8 * (r >> 2) + 4 * lhi;
        TG[rowl * 66 + l31]      = ac0[r];   // cols 0..31  (gates i,f)
        TG[rowl * 66 + 32 + l31] = ac1[r];   // cols 32..63 (gates g,o)
      }
    }
    __syncthreads();   // GL ready

    // ---- elementwise LSTM: 2 cells per thread ----
    const float* GLr = TG + row * 66;
    const int hl = jd * 2;
    const float i0 = GLr[ 0 + hl]     + bf2f((unsigned short)(gx0 & 0xffff)) + bx0;
    const float i1 = GLr[ 0 + hl + 1] + bf2f((unsigned short)(gx0 >> 16))    + by0;
    const float f0 = GLr[16 + hl]     + bf2f((unsigned short)(gx1 & 0xffff)) + bx1;
    const float f1 = GLr[16 + hl + 1] + bf2f((unsigned short)(gx1 >> 16))    + by1;
    const float g0 = GLr[32 + hl]     + bf2f((unsigned short)(gx2 & 0xffff)) + bx2;
    const float g1 = GLr[32 + hl + 1] + bf2f((unsigned short)(gx2 >> 16))    + by2;
    const float o0 = GLr[48 + hl]     + bf2f((unsigned short)(gx3 & 0xffff)) + bx3;
    const float o1 = GLr[48 + hl + 1] + bf2f((unsigned short)(gx3 >> 16))    + by3;
    const float cox = rc ? 0.f : ccx;
    const float coy = rc ? 0.f : ccy;
    const float ncx = sigm(f0) * cox + sigm(i0) * ftanh(g0);
    const float ncy = sigm(f1) * coy + sigm(i1) * ftanh(g1);
    const float nhx = sigm(o0) * ftanh(ncx);
    const float nhy = sigm(o1) * ftanh(ncy);
    ccx = ncx; ccy = ncy;

    // ---- publish h (4B coherent store) + flag, then out stores ----
    if (t + 1 < TT) {
      const float hx = rn ? 0.f : nhx, hy = rn ? 0.f : nhy;
      unsigned int hp;
      asm("v_cvt_pk_bf16_f32 %0, %1, %2" : "=v"(hp) : "v"(hx), "v"(hy));
      char* dst = (char*)hbufB + (size_t)((t + 1) & 1) * HSLOT3
                + (size_t)g * 65536 + puboff;
      asm volatile("global_store_dword %0, %1, off sc0 sc1" :: "v"(dst), "v"(hp) : "memory");
      asm volatile("s_waitcnt vmcnt(0)" ::: "memory");
      __syncthreads();
      if (tid == 0) {
        unsigned int* fp = flags + bid;
        const unsigned int val = (unsigned int)(t + 2);
        asm volatile("global_store_dword %0, %1, off sc0 sc1" :: "v"(fp), "v"(val) : "memory");
      }
      float* op = out + (size_t)t * BB * HH + (size_t)grow * HH + hc;
      op[0] = nhx; op[1] = nhy;
    } else {
      float* op = out + (size_t)t * BB * HH + (size_t)grow * HH + hc;
      op[0] = nhx; op[1] = nhy;
      float* hp2 = out + (size_t)TT * BB * HH + (size_t)grow * HH + hc;
      hp2[0] = nhx; hp2[1] = nhy;
      float* cp2 = out + (size_t)TT * BB * HH + (size_t)BB * HH + (size_t)grow * HH + hc;
      cp2[0] = ncx; cp2[1] = ncy;
    }
  }
}

// ---------------- fallback (round-3 kernel, ws too small) ----------------
#define FB_GL_OFF 131072
#define FB_HN_OFF 147968
#define FB_SMEM   150016

#define FB_HLD(dst, KH) asm volatile("global_load_dwordx4 %0, %1, off sc0 sc1" \
    : "=v"(dst) : "v"(hbB + (size_t)(KH) * 64) : "memory")
#define FB_HSTEP(IT, WCA, WCB) do {                                                  \
  asm volatile("s_waitcnt vmcnt(" WCA ")" ::: "memory");                             \
  __builtin_amdgcn_sched_barrier(0);                                                 \
  { const bf8 bbA = *(const bf8*)(sm + (size_t)(128 + 8*(IT) + 2*wk + lhi)*512 + l31*16); \
    acc = __builtin_amdgcn_mfma_f32_32x32x16_bf16(hA, bbA, acc, 0, 0, 0); }          \
  if ((IT) < 15) FB_HLD(hA, 2*(IT) + 2);                                             \
  asm volatile("s_waitcnt vmcnt(" WCB ")" ::: "memory");                             \
  __builtin_amdgcn_sched_barrier(0);                                                 \
  { const bf8 bbB = *(const bf8*)(sm + (size_t)(128 + 8*(IT) + 4 + 2*wk + lhi)*512 + l31*16); \
    acc = __builtin_amdgcn_mfma_f32_32x32x16_bf16(hB, bbB, acc, 0, 0, 0); }          \
  if ((IT) < 15) FB_HLD(hB, 2*(IT) + 3);                                             \
} while (0)

__global__ void __launch_bounds__(512)
k_scan_fb(const float* __restrict__ obs, const unsigned char* __restrict__ resetsB,
          const int* __restrict__ resetsI, const float* __restrict__ c0,
          const float* __restrict__ bias, const unsigned short* __restrict__ Wp,
          unsigned short* __restrict__ hbuf, unsigned int* __restrict__ flags,
          const int* __restrict__ flagmode, float* __restrict__ out) {
  extern __shared__ char sm[];
  float* GLf = (float*)(sm + FB_GL_OFF);
  unsigned short* HNp = (unsigned short*)(sm + FB_HN_OFF);

  const int tid = threadIdx.x;
  const int w   = tid >> 6;
  const int wm  = w >> 1;
  const int wk  = w & 1;
  const int ln  = tid & 63;
  const int l31 = ln & 31;
  const int lhi = ln >> 5;
  const int b   = blockIdx.x;
  const int byteMode = *flagmode;

  {
    const int np_ld = tid >> 4;
    const int seg   = tid & 15;
    const int gq = np_ld >> 3, jj = np_ld & 7;
    const unsigned short* src = Wp + (size_t)(gq * 1024 + b * 8 + jj) * KT;
#pragma unroll 4
    for (int i = 0; i < 16; ++i) {
      const int k8 = seg * 16 + i;
      bf8 v = *(const bf8*)(src + k8 * 8);
      *(bf8*)(sm + (size_t)k8 * 512 + np_ld * 16) = v;
    }
  }

  const int j  = tid & 7;
  const int rl = tid >> 3;
  float c_a = c0[(size_t)rl * HH + b * 8 + j];
  float c_b = c0[(size_t)(rl + 64) * HH + b * 8 + j];
  const float wbias = bias[(l31 >> 3) * 1024 + b * 8 + (l31 & 7)];

  __syncthreads();

#pragma unroll 1
  for (int t = 0; t < TT; ++t) {
    bool rc0, rc1, rn0 = false, rn1 = false;
    if (byteMode) {
      rc0 = resetsB[t * BB + rl] != 0;  rc1 = resetsB[t * BB + rl + 64] != 0;
      if (t + 1 < TT) { rn0 = resetsB[(t+1)*BB + rl] != 0; rn1 = resetsB[(t+1)*BB + rl + 64] != 0; }
    } else {
      rc0 = resetsI[t * BB + rl] != 0;  rc1 = resetsI[t * BB + rl + 64] != 0;
      if (t + 1 < TT) { rn0 = resetsI[(t+1)*BB + rl] != 0; rn1 = resetsI[(t+1)*BB + rl + 64] != 0; }
    }

    f32x16 acc = {0.f,0.f,0.f,0.f, 0.f,0.f,0.f,0.f, 0.f,0.f,0.f,0.f, 0.f,0.f,0.f,0.f};

    {
      const float* xbase = obs + ((size_t)t * BB + wm * 32 + l31) * DD + wk * 16 + lhi * 8;
#pragma unroll 8
      for (int ks = 0; ks < 32; ++ks) {
        const float* xp = xbase + ks * 32;
        f32x4 f0 = *(const f32x4*)xp;
        f32x4 f1 = *(const f32x4*)(xp + 4);
        uint4 cv;
        asm("v_cvt_pk_bf16_f32 %0, %1, %2" : "=v"(cv.x) : "v"(f0[0]), "v"(f0[1]));
        asm("v_cvt_pk_bf16_f32 %0, %1, %2" : "=v"(cv.y) : "v"(f0[2]), "v"(f0[3]));
        asm("v_cvt_pk_bf16_f32 %0, %1, %2" : "=v"(cv.z) : "v"(f1[0]), "v"(f1[1]));
        asm("v_cvt_pk_bf16_f32 %0, %1, %2" : "=v"(cv.w) : "v"(f1[2]), "v"(f1[3]));
        const bf8 xa = __builtin_bit_cast(bf8, cv);
        const bf8 xb = *(const bf8*)(sm + (size_t)(4 * ks + 2 * wk + lhi) * 512 + l31 * 16);
        acc = __builtin_amdgcn_mfma_f32_32x32x16_bf16(xa, xb, acc, 0, 0, 0);
      }
    }

    {
      const unsigned long long* f64 = (const unsigned long long*)flags;
      const unsigned int need = (unsigned int)(t + 1);
      while (true) {
        unsigned long long v = __hip_atomic_load(&f64[ln], __ATOMIC_RELAXED,
                                                 __HIP_MEMORY_SCOPE_AGENT);
        const int ok = ((unsigned int)v >= need) && ((unsigned int)(v >> 32) >= need);
        if (__all(ok)) break;
        __builtin_amdgcn_s_sleep(2);
      }
    }
    asm volatile("s_waitcnt vmcnt(0)" ::: "memory");
    __builtin_amdgcn_sched_barrier(0);

    {
      const char* hbB = (const char*)hbuf + (size_t)(t & 1) * (BB * HH * 2)
                      + (size_t)(wm * 32 + l31) * (HH * 2) + (size_t)wk * 32 + (size_t)lhi * 16;
      bf8 hA, hB;
      FB_HLD(hA, 0); FB_HLD(hB, 1);
      FB_HSTEP(0,  "1", "1");  FB_HSTEP(1,  "1", "1");  FB_HSTEP(2,  "1", "1");
      FB_HSTEP(3,  "1", "1");  FB_HSTEP(4,  "1", "1");  FB_HSTEP(5,  "1", "1");
      FB_HSTEP(6,  "1", "1");  FB_HSTEP(7,  "1", "1");  FB_HSTEP(8,  "1", "1");
      FB_HSTEP(9,  "1", "1");  FB_HSTEP(10, "1", "1");  FB_HSTEP(11, "1", "1");
      FB_HSTEP(12, "1", "1");  FB_HSTEP(13, "1", "1");  FB_HSTEP(14, "1", "1");
      FB_HSTEP(15, "1", "0");
    }

    if (wk == 1) {
      char* tp = sm + FB_GL_OFF + wm * 4096 + ln * 16;
      f32x4 v0 = {acc[0], acc[1], acc[2], acc[3]};
      f32x4 v1 = {acc[4], acc[5], acc[6], acc[7]};
      f32x4 v2 = {acc[8], acc[9], acc[10], acc[11]};
      f32x4 v3 = {acc[12], acc[13], acc[14], acc[15]};
      *(f32x4*)(tp)        = v0;  *(f32x4*)(tp + 1024) = v1;
      *(f32x4*)(tp + 2048) = v2;  *(f32x4*)(tp + 3072) = v3;
    }
    __syncthreads();
    f32x4 r0, r1, r2, r3;
    if (wk == 0) {
      const char* tp = sm + FB_GL_OFF + wm * 4096 + ln * 16;
      r0 = *(const f32x4*)(tp);        r1 = *(const f32x4*)(tp + 1024);
      r2 = *(const f32x4*)(tp + 2048); r3 = *(const f32x4*)(tp + 3072);
    }
    __syncthreads();
    if (wk == 0) {
#pragma unroll
      for (int r = 0; r < 16; ++r) {
        const float add = (r < 4) ? r0[r & 3] : (r < 8) ? r1[r & 3]
                        : (r < 12) ? r2[r & 3] : r3[r & 3];
        const int rowl = wm * 32 + (r & 3) + 8 * (r >> 2) + 4 * lhi;
        GLf[rowl * 33 + l31] = acc[r] + add + wbias;
      }
    }
    __syncthreads();

    {
      {
        const int row = rl;
        float cold = rc0 ? 0.f : c_a;
        const float ig = GLf[row * 33 + j],      fg = GLf[row * 33 + 8 + j];
        const float gg = GLf[row * 33 + 16 + j], og = GLf[row * 33 + 24 + j];
        const float nc = sigm(fg) * cold + sigm(ig) * ftanh(gg);
        const float nh = sigm(og) * ftanh(nc);
        c_a = nc;
        out[(size_t)t * BB * HH + (size_t)row * HH + b * 8 + j] = nh;
        HNp[row * 8 + j] = rn0 ? (unsigned short)0 : f2bf(nh);
        if (t == TT - 1) {
          out[(size_t)TT * BB * HH + (size_t)row * HH + b * 8 + j] = nh;
          out[(size_t)TT * BB * HH + (size_t)BB * HH + (size_t)row * HH + b * 8 + j] = nc;
        }
      }
      {
        const int row = rl + 64;
        float cold = rc1 ? 0.f : c_b;
        const float ig = GLf[row * 33 + j],      fg = GLf[row * 33 + 8 + j];
        const float gg = GLf[row * 33 + 16 + j], og = GLf[row * 33 + 24 + j];
        const float nc = sigm(fg) * cold + sigm(ig) * ftanh(gg);
        const float nh = sigm(og) * ftanh(nc);
        c_b = nc;
        out[(size_t)t * BB * HH + (size_t)row * HH + b * 8 + j] = nh;
        HNp[row * 8 + j] = rn1 ? (unsigned short)0 : f2bf(nh);
        if (t == TT - 1) {
          out[(size_t)TT * BB * HH + (size_t)row * HH + b * 8 + j] = nh;
          out[(size_t)TT * BB * HH + (size_t)BB * HH + (size_t)row * HH + b * 8 + j] = nc;
        }
      }
    }
    __syncthreads();

    if (t + 1 < TT) {
      if (tid < BB) {
        const bf8 hv = *(const bf8*)(sm + FB_HN_OFF + tid * 16);
        char* dst = (char*)hbuf + (size_t)((t + 1) & 1) * (BB * HH * 2)
                  + (size_t)tid * (HH * 2) + (size_t)b * 16;
        asm volatile("global_store_dwordx4 %0, %1, off sc0 sc1" :: "v"(dst), "v"(hv) : "memory");
      }
      asm volatile("s_waitcnt vmcnt(0)" ::: "memory");
      __syncthreads();
      if (tid == 0) {
        unsigned int* fp = flags + b;
        const unsigned int val = (unsigned int)(t + 2);
        asm volatile("global_store_dword %0, %1, off sc0 sc1" :: "v"(fp), "v"(val) : "memory");
      }
    }
  }
}

// ---------------- launch ----------------

extern "C" void kernel_launch(void* const* d_in, const int* in_sizes, int n_in,
                              void* d_out, int out_size, void* d_ws, size_t ws_size,
                              hipStream_t stream) {
  const float* obs  = (const float*)d_in[0];
  const void*  rst  = d_in[1];
  const float* h0   = (const float*)d_in[2];
  const float* c0   = (const float*)d_in[3];
  const float* Wx   = (const float*)d_in[4];
  const float* Wh   = (const float*)d_in[5];
  const float* bias = (const float*)d_in[6];
  float* out = (float*)d_out;

  char* ws = (char*)d_ws;
  const size_t WP_OFF    = 0;                                   // 16 MiB
  const size_t HBUF_OFF  = (size_t)16 << 20;                    // 0.5 MiB (fallback)
  const size_t FLAGS_OFF = HBUF_OFF + ((size_t)512 << 10);
  const size_t HBUFB_OFF = (size_t)17 << 20;                    // 0.5 MiB (staged layout)
  const size_t OBSBF_OFF = (size_t)24 << 20;                    // 128 MiB
  const size_t GX_OFF    = OBSBF_OFF + ((size_t)128 << 20);     // 512 MiB
  const size_t WS_NEED   = GX_OFF + (size_t)TT * BB * NG * 2;

  unsigned short* Wp    = (unsigned short*)(ws + WP_OFF);
  unsigned short* hbuf  = (unsigned short*)(ws + HBUF_OFF);
  unsigned int*   flags = (unsigned int*)(ws + FLAGS_OFF);
  int*        flagmode  = (int*)(flags + 256);
  unsigned short* hbufB = (unsigned short*)(ws + HBUFB_OFF);
  unsigned short* obsbf = (unsigned short*)(ws + OBSBF_OFF);
  unsigned short* gxp   = (unsigned short*)(ws + GX_OFF);

  const unsigned char* rB = (const unsigned char*)rst;
  const int* rI = (const int*)rst;

  k_detect<<<1, 256, 0, stream>>>((const unsigned int*)rst, flagmode, flags);
  k_pack<<<dim3((KT / 64) * (NG / 64)), dim3(256), 0, stream>>>(Wx, Wh, Wp);

  if (ws_size >= WS_NEED) {
    k_initB3<<<dim3((BB * HH) / 256), dim3(256), 0, stream>>>(h0, rB, rI, flagmode, hbufB);
    k_cvt<<<dim3(2048), dim3(256), 0, stream>>>(obs, obsbf);
    hipFuncSetAttribute((const void*)k_gemm,
                        hipFuncAttributeMaxDynamicSharedMemorySize, GEMM_SMEM);
    k_gemm<<<dim3((TT * BB / 128) * (NG / 128)), dim3(256), GEMM_SMEM, stream>>>(
        obsbf, Wp, gxp);
    hipFuncSetAttribute((const void*)k_scanh3,
                        hipFuncAttributeMaxDynamicSharedMemorySize, SCANH3_SMEM);
    void* args3[] = { (void*)&rB, (void*)&rI, (void*)&c0, (void*)&bias, (void*)&Wp,
                      (void*)&gxp, (void*)&hbufB, (void*)&flags, (void*)&flagmode,
                      (void*)&out };
    hipLaunchCooperativeKernel((const void*)k_scanh3, dim3(256), dim3(256), args3,
                               SCANH3_SMEM, stream);
  } else {
    k_init<<<dim3((BB * HH) / 256), dim3(256), 0, stream>>>(h0, rB, rI, flagmode, hbuf);
    hipFuncSetAttribute((const void*)k_scan_fb,
                        hipFuncAttributeMaxDynamicSharedMemorySize, FB_SMEM);
    k_scan_fb<<<dim3(128), dim3(512), FB_SMEM, stream>>>(
        obs, rB, rI, c0, bias, Wp, hbuf, flags, flagmode, out);
  }
}